// Round 1
// baseline (1998.009 us; speedup 1.0000x reference)
//
#include <hip/hip_runtime.h>
#include <math.h>

#define Hh     32
#define Pp     64
#define HIDc   1024
#define Nn     128
#define CSc    256
#define INTERc 2048
#define CONVDc 2304
#define PROJc  4384
#define Bb     2
#define Ss     2048
#define Tt     4096
#define NCc    8

// ---------------- GEMM: C[M,N] = A[M,K] * B[N,K]^T + bias[N] ----------------
// A,B row-major (k contiguous). M % 128 == 0, K % 16 == 0, N guarded.
__global__ __launch_bounds__(256)
void gemm_tn(const float* __restrict__ A, const float* __restrict__ Bm,
             const float* __restrict__ bias, float* __restrict__ C,
             int M, int N, int K) {
  const int BM = 128, BN = 128, BK = 16;
  __shared__ float As[16][132];
  __shared__ float Bs[16][132];
  const int tid = threadIdx.x;
  const int tx = tid & 15, ty = tid >> 4;
  const int row0 = blockIdx.y * BM, col0 = blockIdx.x * BN;
  const int am = tid >> 1;          // 0..127 row within tile
  const int ak = (tid & 1) << 3;    // 0 or 8
  float acc[8][8];
#pragma unroll
  for (int i = 0; i < 8; ++i)
#pragma unroll
    for (int j = 0; j < 8; ++j) acc[i][j] = 0.f;

  for (int k0 = 0; k0 < K; k0 += BK) {
    {
      const float* src = A + (size_t)(row0 + am) * K + k0 + ak;
      float4 v0 = *(const float4*)src;
      float4 v1 = *(const float4*)(src + 4);
      As[ak+0][am]=v0.x; As[ak+1][am]=v0.y; As[ak+2][am]=v0.z; As[ak+3][am]=v0.w;
      As[ak+4][am]=v1.x; As[ak+5][am]=v1.y; As[ak+6][am]=v1.z; As[ak+7][am]=v1.w;
    }
    {
      const int bn = col0 + am;
      float4 v0 = make_float4(0.f,0.f,0.f,0.f), v1 = v0;
      if (bn < N) {
        const float* src = Bm + (size_t)bn * K + k0 + ak;
        v0 = *(const float4*)src;
        v1 = *(const float4*)(src + 4);
      }
      Bs[ak+0][am]=v0.x; Bs[ak+1][am]=v0.y; Bs[ak+2][am]=v0.z; Bs[ak+3][am]=v0.w;
      Bs[ak+4][am]=v1.x; Bs[ak+5][am]=v1.y; Bs[ak+6][am]=v1.z; Bs[ak+7][am]=v1.w;
    }
    __syncthreads();
#pragma unroll
    for (int kk = 0; kk < BK; ++kk) {
      float a[8], b[8];
      *(float4*)&a[0] = *(const float4*)&As[kk][ty*8];
      *(float4*)&a[4] = *(const float4*)&As[kk][ty*8+4];
      *(float4*)&b[0] = *(const float4*)&Bs[kk][tx*8];
      *(float4*)&b[4] = *(const float4*)&Bs[kk][tx*8+4];
#pragma unroll
      for (int i = 0; i < 8; ++i)
#pragma unroll
        for (int j = 0; j < 8; ++j) acc[i][j] += a[i]*b[j];
    }
    __syncthreads();
  }
#pragma unroll
  for (int i = 0; i < 8; ++i) {
    const int r = row0 + ty*8 + i;
#pragma unroll
    for (int j = 0; j < 8; ++j) {
      const int ccol = col0 + tx*8 + j;
      if (ccol < N) C[(size_t)r*N + ccol] = acc[i][j] + bias[ccol];
    }
  }
}

// ---------------- causal depthwise conv (K=4) + silu ----------------
__global__ __launch_bounds__(256)
void conv_silu(const float* __restrict__ proj, const float* __restrict__ cw,
               float* __restrict__ conv) {
  const int idx = blockIdx.x * 256 + threadIdx.x;
  if (idx >= Tt * CONVDc) return;
  const int ch = idx % CONVDc;
  const int t  = idx / CONVDc;
  const int s  = t & (Ss - 1);
  const float4 w = *(const float4*)&cw[ch << 2];
  const float* col = proj + (size_t)t * PROJc + INTERc + ch;
  float acc;
  if (s >= 3) {
    acc = col[-(ptrdiff_t)3*PROJc]*w.x + col[-(ptrdiff_t)2*PROJc]*w.y
        + col[-(ptrdiff_t)PROJc]*w.z + col[0]*w.w;
  } else {
    acc = col[0]*w.w;
    if (s >= 1) acc += col[-(ptrdiff_t)PROJc]*w.z;
    if (s >= 2) acc += col[-(ptrdiff_t)2*PROJc]*w.y;
  }
  conv[idx] = acc / (1.f + __expf(-acc));
}

// ---------------- dt softplus + A*dt ----------------
__global__ __launch_bounds__(256)
void dt_kernel(const float* __restrict__ proj, const float* __restrict__ dt_bias,
               const float* __restrict__ A_log, float* __restrict__ dtv,
               float* __restrict__ adt) {
  const int idx = blockIdx.x * 256 + threadIdx.x;   // T*H
  const int hh = idx & (Hh - 1);
  const int t  = idx >> 5;
  float xv = proj[(size_t)t * PROJc + INTERc + CONVDc + hh] + dt_bias[hh];
  float sp = (xv > 20.f) ? xv : log1pf(__expf(xv));
  dtv[idx] = sp;
  adt[idx] = -__expf(A_log[hh]) * sp;
}

// ---------------- B/C transpose to [b][n][s] ----------------
__global__ __launch_bounds__(256)
void bc_transpose(const float* __restrict__ conv, float* __restrict__ Bt,
                  float* __restrict__ Ct) {
  const int idx = blockIdx.x * 256 + threadIdx.x;   // Bb*Nn*Ss
  const int s = idx & (Ss - 1);
  const int n = (idx >> 11) & (Nn - 1);
  const int b = idx >> 18;
  const size_t src = (size_t)(b * Ss + s) * CONVDc + INTERc;
  Bt[idx] = conv[src + n];
  Ct[idx] = conv[src + Nn + n];
}

// ---------------- G (transposed): Gt[bc][s][l] = sum_n C[l][n]*B[s][n], s<=l ----------------
__global__ __launch_bounds__(256)
void g_kernel(const float* __restrict__ Bt, const float* __restrict__ Ct,
              float* __restrict__ Gt) {
  const int bc = blockIdx.z;           // 0..15
  const int b = bc >> 3;
  const int c = bc & 7;
  const int l = blockIdx.y * 64 + (threadIdx.x & 63);
  const int s = blockIdx.x * 4 + (threadIdx.x >> 6);
  if (s > l) return;
  const int t0 = c * CSc;
  const float* cp = Ct + (size_t)b * Nn * Ss + t0 + l;
  const float* bp = Bt + (size_t)b * Nn * Ss + t0 + s;
  float acc = 0.f;
#pragma unroll 4
  for (int n = 0; n < Nn; ++n) acc += cp[(size_t)n * Ss] * bp[(size_t)n * Ss];
  Gt[((size_t)bc * CSc + s) * CSc + l] = acc;
}

#define ACC16(W, PTR)                                                          \
  {                                                                            \
    const float4* _p = (const float4*)(PTR);                                   \
    float4 _a = _p[0], _b = _p[1], _c = _p[2], _d = _p[3];                     \
    const float _w = (W);                                                      \
    acc[0] += _w*_a.x;  acc[1] += _w*_a.y;  acc[2] += _w*_a.z;  acc[3] += _w*_a.w; \
    acc[4] += _w*_b.x;  acc[5] += _w*_b.y;  acc[6] += _w*_b.z;  acc[7] += _w*_b.w; \
    acc[8] += _w*_c.x;  acc[9] += _w*_c.y;  acc[10]+= _w*_c.z;  acc[11]+= _w*_c.w; \
    acc[12]+= _w*_d.x;  acc[13]+= _w*_d.y;  acc[14]+= _w*_d.z;  acc[15]+= _w*_d.w; \
  }

// ---------------- SSD scan: one block per (b,h,p-split-of-4) ----------------
__global__ __launch_bounds__(256)
void ssd_kernel(const float* __restrict__ conv, const float* __restrict__ dtv,
                const float* __restrict__ adt, const float* __restrict__ Gt,
                const float* __restrict__ Ct, const float* __restrict__ Dp,
                float* __restrict__ Y) {
  const int blk = blockIdx.x;          // 256 = 2*32*4
  const int pb = blk & 3;
  const int h  = (blk >> 2) & 31;
  const int b  = blk >> 7;
  const int p0 = pb * 16;
  const int tid = threadIdx.x;
  const int lane = tid & 63, wv = tid >> 6;

  __shared__ float stateT[Nn][16];   // [n][pp]
  __shared__ float hr[CSc][16];      // raw h tile
  __shared__ float acum[CSc];
  __shared__ float dts[CSc];
  __shared__ float wdec[CSc];
  __shared__ float wsum[4];

  for (int i = tid; i < Nn * 16; i += 256) ((float*)stateT)[i] = 0.f;
  const float Dh = Dp[h];
  __syncthreads();

  for (int c = 0; c < NCc; ++c) {
    const int tg = b * Ss + c * CSc;   // global token base
    const int sb = c * CSc;            // within-batch base
    // ---- stage dts + inclusive scan of A*dt ----
    {
      float av = adt[(size_t)(tg + tid) * Hh + h];
      float dv = dtv[(size_t)(tg + tid) * Hh + h];
      dts[tid] = dv;
      float v = av;
#pragma unroll
      for (int off = 1; off < 64; off <<= 1) {
        float u = __shfl_up(v, off);
        if (lane >= off) v += u;
      }
      if (lane == 63) wsum[wv] = v;
      __syncthreads();
      float offacc = 0.f;
      for (int w = 0; w < wv; ++w) offacc += wsum[w];
      acum[tid] = v + offacc;
      __syncthreads();
    }
    // ---- stage hr + decay weights ----
    {
      const float atot = acum[CSc - 1];
      wdec[tid] = __expf(atot - acum[tid]) * dts[tid];
      for (int i = tid; i < CSc * 16; i += 256) {
        const int l = i >> 4, pp = i & 15;
        hr[l][pp] = conv[(size_t)(tg + l) * CONVDc + h * Pp + p0 + pp];
      }
    }
    __syncthreads();

    // ---- Y_off + Y_diag for row l = tid ----
    {
      const int l = tid;
      float acc[16];
#pragma unroll
      for (int q = 0; q < 16; ++q) acc[q] = 0.f;
      // Y_off: exp(acum[l]) * sum_n C[l][n] * state[n][pp]
      {
        const float* cp = Ct + (size_t)b * Nn * Ss + sb + l;
#pragma unroll 4
        for (int n = 0; n < Nn; ++n) {
          float cv = cp[(size_t)n * Ss];
          ACC16(cv, &stateT[n][0]);
        }
        const float el = __expf(acum[l]);
#pragma unroll
        for (int q = 0; q < 16; ++q) acc[q] *= el;
      }
      // Y_diag: sum_{s<=l} G[l][s]*exp(acum[l]-acum[s])*dt[s]*hraw[s][pp]
      {
        const float al = acum[l];
        const float* gp = Gt + ((size_t)(b * NCc + c) * CSc) * CSc + l;
        for (int s = 0; s <= l; ++s) {
          float w = gp[(size_t)s * CSc] * __expf(al - acum[s]) * dts[s];
          ACC16(w, &hr[s][0]);
        }
      }
      // D residual (uses UNSCALED h) + store
      {
        ACC16(Dh, &hr[l][0]);
        float* yp = Y + (size_t)(tg + l) * INTERc + h * Pp + p0;
        ((float4*)yp)[0] = make_float4(acc[0], acc[1], acc[2], acc[3]);
        ((float4*)yp)[1] = make_float4(acc[4], acc[5], acc[6], acc[7]);
        ((float4*)yp)[2] = make_float4(acc[8], acc[9], acc[10], acc[11]);
        ((float4*)yp)[3] = make_float4(acc[12], acc[13], acc[14], acc[15]);
      }
    }
    __syncthreads();

    // ---- state update: state = state*exp(atot) + sum_l wdec[l]*hraw[l][p]*B[l][n] ----
    {
      const float cd = __expf(acum[CSc - 1]);
      const int pp = tid >> 4, ni = tid & 15;
      float st[8];
#pragma unroll
      for (int i = 0; i < 8; ++i) st[i] = stateT[ni + 16 * i][pp] * cd;
      const float* bbase = conv + (size_t)tg * CONVDc + INTERc + ni;
      for (int lq = 0; lq < CSc; ++lq) {
        const float wl = wdec[lq] * hr[lq][pp];
        const float* bp = bbase + (size_t)lq * CONVDc;
#pragma unroll
        for (int i = 0; i < 8; ++i) st[i] += wl * bp[16 * i];
      }
#pragma unroll
      for (int i = 0; i < 8; ++i) stateT[ni + 16 * i][pp] = st[i];
    }
    __syncthreads();
  }
}

// ---------------- gate * silu + RMSNorm ----------------
__global__ __launch_bounds__(256)
void gate_norm(const float* __restrict__ Y, const float* __restrict__ proj,
               const float* __restrict__ nw, float* __restrict__ g) {
  const int t = blockIdx.x;
  const int tid = threadIdx.x;
  const int lane = tid & 63, wv = tid >> 6;
  __shared__ float ws4[4];
  const float* yp = Y + (size_t)t * INTERc;
  const float* gp = proj + (size_t)t * PROJc;
  float vals[8];
  float ss = 0.f;
#pragma unroll
  for (int i = 0; i < 8; ++i) {
    const int cix = tid + (i << 8);
    float yv = yp[cix];
    float gv = gp[cix];
    float vv = yv * (gv / (1.f + __expf(-gv)));
    vals[i] = vv;
    ss += vv * vv;
  }
#pragma unroll
  for (int off = 32; off > 0; off >>= 1) ss += __shfl_xor(ss, off);
  if (lane == 0) ws4[wv] = ss;
  __syncthreads();
  const float tot = ws4[0] + ws4[1] + ws4[2] + ws4[3];
  const float sc = rsqrtf(tot * (1.f / INTERc) + 1e-5f);
  float* go = g + (size_t)t * INTERc;
#pragma unroll
  for (int i = 0; i < 8; ++i) {
    const int cix = tid + (i << 8);
    go[cix] = vals[i] * sc * nw[cix];
  }
}

extern "C" void kernel_launch(void* const* d_in, const int* in_sizes, int n_in,
                              void* d_out, int out_size, void* d_ws, size_t ws_size,
                              hipStream_t stream) {
  (void)in_sizes; (void)n_in; (void)out_size; (void)ws_size;
  const float* x       = (const float*)d_in[0];
  const float* W_in    = (const float*)d_in[1];
  const float* b_in    = (const float*)d_in[2];
  const float* conv_w  = (const float*)d_in[3];
  const float* dt_bias = (const float*)d_in[4];
  const float* A_log   = (const float*)d_in[5];
  const float* Dp      = (const float*)d_in[6];
  const float* norm_w  = (const float*)d_in[7];
  const float* W_out   = (const float*)d_in[8];
  const float* b_out   = (const float*)d_in[9];
  float* out = (float*)d_out;

  float* proj = (float*)d_ws;
  float* conv = proj + (size_t)Tt * PROJc;
  float* dtv  = conv + (size_t)Tt * CONVDc;
  float* adt  = dtv  + (size_t)Tt * Hh;
  float* Bt   = adt  + (size_t)Tt * Hh;
  float* Ct   = Bt   + (size_t)Bb * Nn * Ss;
  float* Gt   = Ct   + (size_t)Bb * Nn * Ss;
  float* Ybuf = Gt   + (size_t)Bb * NCc * CSc * CSc;
  float* gbuf = Ybuf + (size_t)Tt * INTERc;

  // 1. proj = x @ W_in^T + b_in
  gemm_tn<<<dim3((PROJc + 127) / 128, Tt / 128), 256, 0, stream>>>(
      x, W_in, b_in, proj, Tt, PROJc, HIDc);
  // 2. conv + silu
  conv_silu<<<(Tt * CONVDc) / 256, 256, 0, stream>>>(proj, conv_w, conv);
  // 3. dt
  dt_kernel<<<(Tt * Hh) / 256, 256, 0, stream>>>(proj, dt_bias, A_log, dtv, adt);
  // 4. B/C transpose
  bc_transpose<<<(Bb * Nn * Ss) / 256, 256, 0, stream>>>(conv, Bt, Ct);
  // 5. G matrix (transposed storage, lower tri only)
  g_kernel<<<dim3(64, 4, 16), 256, 0, stream>>>(Bt, Ct, Gt);
  // 6. SSD scan
  ssd_kernel<<<256, 256, 0, stream>>>(conv, dtv, adt, Gt, Ct, Dp, Ybuf);
  // 7. gate + RMSNorm
  gate_norm<<<Tt, 256, 0, stream>>>(Ybuf, proj, norm_w, gbuf);
  // 8. out = g @ W_out^T + b_out
  gemm_tn<<<dim3(HIDc / 128, Tt / 128), 256, 0, stream>>>(
      gbuf, W_out, b_out, out, Tt, HIDc, INTERc);
}

// Round 3
// 1199.728 us; speedup vs baseline: 1.6654x; 1.6654x over previous
//
#include <hip/hip_runtime.h>
#include <math.h>

#define Hh     32
#define Pp     64
#define HIDc   1024
#define Nn     128
#define CSc    256
#define INTERc 2048
#define CONVDc 2304
#define PROJc  4384
#define Bb     2
#define Ss     2048
#define Tt     4096
#define NCc    8

// ---------------- GEMM: C[M,N] = A[M,K] * B[N,K]^T + bias[N] ----------------
__global__ __launch_bounds__(256)
void gemm_tn(const float* __restrict__ A, const float* __restrict__ Bm,
             const float* __restrict__ bias, float* __restrict__ C,
             int M, int N, int K) {
  const int BM = 128, BN = 128, BK = 16;
  __shared__ float As[16][132];
  __shared__ float Bs[16][132];
  const int tid = threadIdx.x;
  const int tx = tid & 15, ty = tid >> 4;
  const int row0 = blockIdx.y * BM, col0 = blockIdx.x * BN;
  const int am = tid >> 1;
  const int ak = (tid & 1) << 3;
  float acc[8][8];
#pragma unroll
  for (int i = 0; i < 8; ++i)
#pragma unroll
    for (int j = 0; j < 8; ++j) acc[i][j] = 0.f;

  for (int k0 = 0; k0 < K; k0 += BK) {
    {
      const float* src = A + (size_t)(row0 + am) * K + k0 + ak;
      float4 v0 = *(const float4*)src;
      float4 v1 = *(const float4*)(src + 4);
      As[ak+0][am]=v0.x; As[ak+1][am]=v0.y; As[ak+2][am]=v0.z; As[ak+3][am]=v0.w;
      As[ak+4][am]=v1.x; As[ak+5][am]=v1.y; As[ak+6][am]=v1.z; As[ak+7][am]=v1.w;
    }
    {
      const int bn = col0 + am;
      float4 v0 = make_float4(0.f,0.f,0.f,0.f), v1 = v0;
      if (bn < N) {
        const float* src = Bm + (size_t)bn * K + k0 + ak;
        v0 = *(const float4*)src;
        v1 = *(const float4*)(src + 4);
      }
      Bs[ak+0][am]=v0.x; Bs[ak+1][am]=v0.y; Bs[ak+2][am]=v0.z; Bs[ak+3][am]=v0.w;
      Bs[ak+4][am]=v1.x; Bs[ak+5][am]=v1.y; Bs[ak+6][am]=v1.z; Bs[ak+7][am]=v1.w;
    }
    __syncthreads();
#pragma unroll
    for (int kk = 0; kk < BK; ++kk) {
      float a[8], b[8];
      *(float4*)&a[0] = *(const float4*)&As[kk][ty*8];
      *(float4*)&a[4] = *(const float4*)&As[kk][ty*8+4];
      *(float4*)&b[0] = *(const float4*)&Bs[kk][tx*8];
      *(float4*)&b[4] = *(const float4*)&Bs[kk][tx*8+4];
#pragma unroll
      for (int i = 0; i < 8; ++i)
#pragma unroll
        for (int j = 0; j < 8; ++j) acc[i][j] += a[i]*b[j];
    }
    __syncthreads();
  }
#pragma unroll
  for (int i = 0; i < 8; ++i) {
    const int r = row0 + ty*8 + i;
#pragma unroll
    for (int j = 0; j < 8; ++j) {
      const int ccol = col0 + tx*8 + j;
      if (ccol < N) C[(size_t)r*N + ccol] = acc[i][j] + bias[ccol];
    }
  }
}

// ---------------- causal depthwise conv (K=4) + silu ----------------
__global__ __launch_bounds__(256)
void conv_silu(const float* __restrict__ proj, const float* __restrict__ cw,
               float* __restrict__ conv) {
  const int idx = blockIdx.x * 256 + threadIdx.x;
  if (idx >= Tt * CONVDc) return;
  const int ch = idx % CONVDc;
  const int t  = idx / CONVDc;
  const int s  = t & (Ss - 1);
  const float4 w = *(const float4*)&cw[ch << 2];
  const float* col = proj + (size_t)t * PROJc + INTERc + ch;
  float acc;
  if (s >= 3) {
    acc = col[-(ptrdiff_t)3*PROJc]*w.x + col[-(ptrdiff_t)2*PROJc]*w.y
        + col[-(ptrdiff_t)PROJc]*w.z + col[0]*w.w;
  } else {
    acc = col[0]*w.w;
    if (s >= 1) acc += col[-(ptrdiff_t)PROJc]*w.z;
    if (s >= 2) acc += col[-(ptrdiff_t)2*PROJc]*w.y;
  }
  conv[idx] = acc / (1.f + __expf(-acc));
}

// ---------------- dt softplus + A*dt ----------------
__global__ __launch_bounds__(256)
void dt_kernel(const float* __restrict__ proj, const float* __restrict__ dt_bias,
               const float* __restrict__ A_log, float* __restrict__ dtv,
               float* __restrict__ adt) {
  const int idx = blockIdx.x * 256 + threadIdx.x;   // T*H
  const int hh = idx & (Hh - 1);
  const int t  = idx >> 5;
  float xv = proj[(size_t)t * PROJc + INTERc + CONVDc + hh] + dt_bias[hh];
  float sp = (xv > 20.f) ? xv : log1pf(__expf(xv));
  dtv[idx] = sp;
  adt[idx] = -__expf(A_log[hh]) * sp;
}

// ---------------- per-(b,c,h) inclusive scan of A*dt ----------------
__global__ __launch_bounds__(256)
void scan_kernel(const float* __restrict__ adt, const float* __restrict__ dtv,
                 float* __restrict__ acumb, float* __restrict__ dtc) {
  const int g = blockIdx.x;          // bc*Hh + h,  512 total
  const int h  = g & (Hh - 1);
  const int bc = g >> 5;
  const int b = bc >> 3, c = bc & 7;
  const int tid = threadIdx.x;
  const int lane = tid & 63, wv = tid >> 6;
  __shared__ float wsum[4];
  const int tg = b * Ss + c * CSc;
  float v  = adt[(size_t)(tg + tid) * Hh + h];
  float dv = dtv[(size_t)(tg + tid) * Hh + h];
#pragma unroll
  for (int off = 1; off < 64; off <<= 1) {
    float u = __shfl_up(v, off);
    if (lane >= off) v += u;
  }
  if (lane == 63) wsum[wv] = v;
  __syncthreads();
  float offacc = 0.f;
  for (int w = 0; w < wv; ++w) offacc += wsum[w];
  acumb[(size_t)g * CSc + tid] = v + offacc;
  dtc[(size_t)g * CSc + tid] = dv;
}

// ---------------- B/C transpose to [b][n][s] ----------------
__global__ __launch_bounds__(256)
void bc_transpose(const float* __restrict__ conv, float* __restrict__ Bt,
                  float* __restrict__ Ct) {
  const int idx = blockIdx.x * 256 + threadIdx.x;   // Bb*Nn*Ss
  const int s = idx & (Ss - 1);
  const int n = (idx >> 11) & (Nn - 1);
  const int b = idx >> 18;
  const size_t src = (size_t)(b * Ss + s) * CONVDc + INTERc;
  Bt[idx] = conv[src + n];
  Ct[idx] = conv[src + Nn + n];
}

// ---------------- G (transposed): Gt[bc][s][l] = sum_n C[l][n]*B[s][n], s<=l ----------------
__global__ __launch_bounds__(256)
void g_kernel(const float* __restrict__ Bt, const float* __restrict__ Ct,
              float* __restrict__ Gt) {
  const int bc = blockIdx.z;           // 0..15
  const int b = bc >> 3;
  const int c = bc & 7;
  const int l = blockIdx.y * 64 + (threadIdx.x & 63);
  const int s = blockIdx.x * 4 + (threadIdx.x >> 6);
  if (s > l) return;
  const int t0 = c * CSc;
  const float* cp = Ct + (size_t)b * Nn * Ss + t0 + l;
  const float* bp = Bt + (size_t)b * Nn * Ss + t0 + s;
  float acc = 0.f;
#pragma unroll 4
  for (int n = 0; n < Nn; ++n) acc += cp[(size_t)n * Ss] * bp[(size_t)n * Ss];
  Gt[((size_t)bc * CSc + s) * CSc + l] = acc;
}

#define ACC16(W, PTR)                                                          \
  {                                                                            \
    const float4* _p = (const float4*)(PTR);                                   \
    float4 _a = _p[0], _b = _p[1], _c = _p[2], _d = _p[3];                     \
    const float _w = (W);                                                      \
    acc[0] += _w*_a.x;  acc[1] += _w*_a.y;  acc[2] += _w*_a.z;  acc[3] += _w*_a.w; \
    acc[4] += _w*_b.x;  acc[5] += _w*_b.y;  acc[6] += _w*_b.z;  acc[7] += _w*_b.w; \
    acc[8] += _w*_c.x;  acc[9] += _w*_c.y;  acc[10]+= _w*_c.z;  acc[11]+= _w*_c.w; \
    acc[12]+= _w*_d.x;  acc[13]+= _w*_d.y;  acc[14]+= _w*_d.z;  acc[15]+= _w*_d.w; \
  }

// ---------------- SSD intra-chunk: Y_diag + D + chunk-local state ----------------
// one block per (b, c, h, p-split-of-4); no inter-chunk dependency
__global__ __launch_bounds__(256)
void ssd_intra(const float* __restrict__ conv, const float* __restrict__ acumb,
               const float* __restrict__ dtc, const float* __restrict__ Gt,
               const float* __restrict__ Dp, float* __restrict__ Y,
               float* __restrict__ S) {
  const int blk = blockIdx.x;          // 2048 = 2*8*32*4
  const int pb = blk & 3;
  const int h  = (blk >> 2) & 31;
  const int c  = (blk >> 7) & 7;
  const int b  = blk >> 10;
  const int p0 = pb * 16;
  const int bc = b * NCc + c;
  const int tg = b * Ss + c * CSc;
  const int tid = threadIdx.x;

  __shared__ float hr[CSc][16];      // raw h tile
  __shared__ float acs[CSc];
  __shared__ float dts[CSc];
  __shared__ float wdec[CSc];

  const float Dh = Dp[h];
  {
    const size_t base = (size_t)(bc * Hh + h) * CSc;
    acs[tid] = acumb[base + tid];
    dts[tid] = dtc[base + tid];
  }
  for (int i = tid; i < CSc * 16; i += 256) {
    const int l = i >> 4, pp = i & 15;
    hr[l][pp] = conv[(size_t)(tg + l) * CONVDc + h * Pp + p0 + pp];
  }
  __syncthreads();
  const float atot = acs[CSc - 1];
  wdec[tid] = __expf(atot - acs[tid]) * dts[tid];
  __syncthreads();

  // ---- Y_diag + D for row l = tid ----
  {
    const int l = tid;
    const float al = acs[l];
    float acc[16];
#pragma unroll
    for (int q = 0; q < 16; ++q) acc[q] = 0.f;
    const float* gp = Gt + (size_t)bc * CSc * CSc + l;
    for (int s = 0; s <= l; ++s) {
      float w = gp[(size_t)s * CSc] * __expf(al - acs[s]) * dts[s];
      ACC16(w, &hr[s][0]);
    }
    ACC16(Dh, &hr[l][0]);
    float* yp = Y + (size_t)(tg + l) * INTERc + h * Pp + p0;
    ((float4*)yp)[0] = make_float4(acc[0], acc[1], acc[2], acc[3]);
    ((float4*)yp)[1] = make_float4(acc[4], acc[5], acc[6], acc[7]);
    ((float4*)yp)[2] = make_float4(acc[8], acc[9], acc[10], acc[11]);
    ((float4*)yp)[3] = make_float4(acc[12], acc[13], acc[14], acc[15]);
  }

  // ---- chunk-local state: S[p][n] = sum_l wdec[l]*hraw[l][p]*B[l][n] ----
  {
    const int pp = tid >> 4, ni = tid & 15;
    float st[8];
#pragma unroll
    for (int i = 0; i < 8; ++i) st[i] = 0.f;
    const float* bbase = conv + (size_t)tg * CONVDc + INTERc + ni;
    for (int lq = 0; lq < CSc; ++lq) {
      const float wl = wdec[lq] * hr[lq][pp];
      const float* bp = bbase + (size_t)lq * CONVDc;
#pragma unroll
      for (int i = 0; i < 8; ++i) st[i] += wl * bp[16 * i];
    }
    float* sp = S + (((size_t)bc * Hh + h) * Pp + p0 + pp) * Nn + ni;
#pragma unroll
    for (int i = 0; i < 8; ++i) sp[16 * i] = st[i];
  }
}

// ---------------- inter-chunk state recurrence (8 steps, elementwise) ----------------
__global__ __launch_bounds__(256)
void state_combine(const float* __restrict__ S, const float* __restrict__ acumb,
                   float* __restrict__ R) {
  const int idx = blockIdx.x * 256 + threadIdx.x;   // Bb*Hh*Pp*Nn = 524288
  const int n = idx & 127;
  const int p = (idx >> 7) & 63;
  const int h = (idx >> 13) & 31;
  const int b = idx >> 18;
  float r = 0.f;
  for (int c = 0; c < NCc; ++c) {
    const int bc = b * NCc + c;
    const size_t off = (((size_t)bc * Hh + h) * Pp + p) * Nn + n;
    R[off] = r;                                     // incoming state for chunk c
    const float atot = acumb[((size_t)bc * Hh + h) * CSc + CSc - 1];
    r = r * __expf(atot) + S[off];
  }
}

// ---------------- SSD off-diagonal: Y += exp(acum)*C·R ----------------
__global__ __launch_bounds__(256)
void ssd_off(const float* __restrict__ Ct, const float* __restrict__ acumb,
             const float* __restrict__ R, float* __restrict__ Y) {
  const int blk = blockIdx.x;          // 2048 = 2*8*32*4
  const int pb = blk & 3;
  const int h  = (blk >> 2) & 31;
  const int c  = (blk >> 7) & 7;
  const int b  = blk >> 10;
  const int p0 = pb * 16;
  const int bc = b * NCc + c;
  const int tg = b * Ss + c * CSc;
  const int tid = threadIdx.x;

  __shared__ float stateT[Nn][20];   // [n][pp], padded to 20 (16B-aligned rows)
  {
    const size_t rbase = (((size_t)bc * Hh + h) * Pp + p0) * Nn;
    for (int i = tid; i < Nn * 16; i += 256) {
      const int pp = i >> 7, n = i & 127;
      stateT[n][pp] = R[rbase + (size_t)pp * Nn + n];
    }
  }
  __syncthreads();
  const int l = tid;
  const float el = __expf(acumb[((size_t)bc * Hh + h) * CSc + l]);
  float acc[16];
#pragma unroll
  for (int q = 0; q < 16; ++q) acc[q] = 0.f;
  const float* cp = Ct + (size_t)b * Nn * Ss + c * CSc + l;
#pragma unroll 4
  for (int n = 0; n < Nn; ++n) {
    float cv = cp[(size_t)n * Ss];
    ACC16(cv, &stateT[n][0]);
  }
  float* yp = Y + (size_t)(tg + l) * INTERc + h * Pp + p0;
  float4 y0 = ((float4*)yp)[0], y1 = ((float4*)yp)[1];
  float4 y2 = ((float4*)yp)[2], y3 = ((float4*)yp)[3];
  ((float4*)yp)[0] = make_float4(y0.x + el*acc[0],  y0.y + el*acc[1],  y0.z + el*acc[2],  y0.w + el*acc[3]);
  ((float4*)yp)[1] = make_float4(y1.x + el*acc[4],  y1.y + el*acc[5],  y1.z + el*acc[6],  y1.w + el*acc[7]);
  ((float4*)yp)[2] = make_float4(y2.x + el*acc[8],  y2.y + el*acc[9],  y2.z + el*acc[10], y2.w + el*acc[11]);
  ((float4*)yp)[3] = make_float4(y3.x + el*acc[12], y3.y + el*acc[13], y3.z + el*acc[14], y3.w + el*acc[15]);
}

// ---------------- gate * silu + RMSNorm ----------------
__global__ __launch_bounds__(256)
void gate_norm(const float* __restrict__ Y, const float* __restrict__ proj,
               const float* __restrict__ nw, float* __restrict__ g) {
  const int t = blockIdx.x;
  const int tid = threadIdx.x;
  const int lane = tid & 63, wv = tid >> 6;
  __shared__ float ws4[4];
  const float* yp = Y + (size_t)t * INTERc;
  const float* gp = proj + (size_t)t * PROJc;
  float vals[8];
  float ss = 0.f;
#pragma unroll
  for (int i = 0; i < 8; ++i) {
    const int cix = tid + (i << 8);
    float yv = yp[cix];
    float gv = gp[cix];
    float vv = yv * (gv / (1.f + __expf(-gv)));
    vals[i] = vv;
    ss += vv * vv;
  }
#pragma unroll
  for (int off = 32; off > 0; off >>= 1) ss += __shfl_xor(ss, off);
  if (lane == 0) ws4[wv] = ss;
  __syncthreads();
  const float tot = ws4[0] + ws4[1] + ws4[2] + ws4[3];
  const float sc = rsqrtf(tot * (1.f / INTERc) + 1e-5f);
  float* go = g + (size_t)t * INTERc;
#pragma unroll
  for (int i = 0; i < 8; ++i) {
    const int cix = tid + (i << 8);
    go[cix] = vals[i] * sc * nw[cix];
  }
}

extern "C" void kernel_launch(void* const* d_in, const int* in_sizes, int n_in,
                              void* d_out, int out_size, void* d_ws, size_t ws_size,
                              hipStream_t stream) {
  (void)in_sizes; (void)n_in; (void)out_size; (void)ws_size;
  const float* x       = (const float*)d_in[0];
  const float* W_in    = (const float*)d_in[1];
  const float* b_in    = (const float*)d_in[2];
  const float* conv_w  = (const float*)d_in[3];
  const float* dt_bias = (const float*)d_in[4];
  const float* A_log   = (const float*)d_in[5];
  const float* Dp      = (const float*)d_in[6];
  const float* norm_w  = (const float*)d_in[7];
  const float* W_out   = (const float*)d_in[8];
  const float* b_out   = (const float*)d_in[9];
  float* out = (float*)d_out;

  float* proj  = (float*)d_ws;
  float* conv  = proj  + (size_t)Tt * PROJc;
  float* dtv   = conv  + (size_t)Tt * CONVDc;
  float* adt   = dtv   + (size_t)Tt * Hh;
  float* Bt    = adt   + (size_t)Tt * Hh;
  float* Ct    = Bt    + (size_t)Bb * Nn * Ss;
  float* Gt    = Ct    + (size_t)Bb * Nn * Ss;
  float* acumb = Gt    + (size_t)Bb * NCc * CSc * CSc;
  float* dtc   = acumb + (size_t)Bb * NCc * Hh * CSc;
  float* Sbuf  = dtc   + (size_t)Bb * NCc * Hh * CSc;
  float* Roff  = Sbuf  + (size_t)Bb * NCc * Hh * Pp * Nn;
  float* Ybuf  = Roff  + (size_t)Bb * NCc * Hh * Pp * Nn;
  float* gbuf  = conv;   // conv dead after ssd_intra; reuse for g

  // 1. proj = x @ W_in^T + b_in
  gemm_tn<<<dim3((PROJc + 127) / 128, Tt / 128), 256, 0, stream>>>(
      x, W_in, b_in, proj, Tt, PROJc, HIDc);
  // 2. conv + silu
  conv_silu<<<(Tt * CONVDc) / 256, 256, 0, stream>>>(proj, conv_w, conv);
  // 3. dt
  dt_kernel<<<(Tt * Hh) / 256, 256, 0, stream>>>(proj, dt_bias, A_log, dtv, adt);
  // 4. chunk-local scan of A*dt
  scan_kernel<<<Bb * NCc * Hh, 256, 0, stream>>>(adt, dtv, acumb, dtc);
  // 5. B/C transpose
  bc_transpose<<<(Bb * Nn * Ss) / 256, 256, 0, stream>>>(conv, Bt, Ct);
  // 6. G matrix (transposed storage, lower tri only)
  g_kernel<<<dim3(64, 4, 16), 256, 0, stream>>>(Bt, Ct, Gt);
  // 7. SSD intra-chunk (Y_diag + D + chunk states)
  ssd_intra<<<Bb * NCc * Hh * 4, 256, 0, stream>>>(conv, acumb, dtc, Gt, Dp,
                                                   Ybuf, Sbuf);
  // 8. inter-chunk recurrence
  state_combine<<<(Bb * Hh * Pp * Nn) / 256, 256, 0, stream>>>(Sbuf, acumb, Roff);
  // 9. SSD off-diagonal
  ssd_off<<<Bb * NCc * Hh * 4, 256, 0, stream>>>(Ct, acumb, Roff, Ybuf);
  // 10. gate + RMSNorm
  gate_norm<<<Tt, 256, 0, stream>>>(Ybuf, proj, norm_w, gbuf);
  // 11. out = g @ W_out^T + b_out
  gemm_tn<<<dim3(HIDc / 128, Tt / 128), 256, 0, stream>>>(
      gbuf, W_out, b_out, out, Tt, HIDc, INTERc);
}

// Round 4
// 520.718 us; speedup vs baseline: 3.8370x; 2.3040x over previous
//
#include <hip/hip_runtime.h>
#include <math.h>

#define Hh     32
#define Pp     64
#define HIDc   1024
#define Nn     128
#define CSc    256
#define INTERc 2048
#define CONVDc 2304
#define PROJc  4384
#define Bb     2
#define Ss     2048
#define Tt     4096
#define NCc    8
#define PROJ_PAD 4480   // PROJc padded up to multiple of 128 for B-staging

typedef __attribute__((ext_vector_type(8))) short short8_t;
typedef __attribute__((ext_vector_type(4))) float f32x4;
typedef unsigned short ushort_t;

__device__ __forceinline__ ushort_t f2b_rtn(float f) {
  unsigned u = __float_as_uint(f);
  unsigned lsb = (u >> 16) & 1u;
  u += 0x7fffu + lsb;
  return (ushort_t)(u >> 16);
}

// ---------------- fp32 -> bf16 (RTN), 8 elems/thread ----------------
__global__ __launch_bounds__(256)
void f2b_kernel(const float* __restrict__ in, ushort_t* __restrict__ out, int n8) {
  const int i = blockIdx.x * 256 + threadIdx.x;
  if (i >= n8) return;
  const float4* ip = (const float4*)in;
  float4 a = ip[2 * i], b = ip[2 * i + 1];
  union { short8_t v; ushort_t h[8]; } u;
  u.h[0] = f2b_rtn(a.x); u.h[1] = f2b_rtn(a.y);
  u.h[2] = f2b_rtn(a.z); u.h[3] = f2b_rtn(a.w);
  u.h[4] = f2b_rtn(b.x); u.h[5] = f2b_rtn(b.y);
  u.h[6] = f2b_rtn(b.z); u.h[7] = f2b_rtn(b.w);
  ((short8_t*)out)[i] = u.v;
}

// ---------------- bf16 MFMA GEMM: C[M,Nr] = A[M,K] * B[Npad,K]^T + bias ----------------
// m97 structure: 128x128 tile, 4 waves of 64x64, mfma 16x16x32, global_load_lds(16B),
// linear LDS (conflict-free at BK=32: b128 frag reads hit all 32 banks evenly).
__global__ __launch_bounds__(256)
void gemm_bf16(const ushort_t* __restrict__ A, const ushort_t* __restrict__ B,
               const float* __restrict__ bias, float* __restrict__ C,
               int M, int Nr, int K) {
  __shared__ ushort_t As[128 * 32];
  __shared__ ushort_t Bs[128 * 32];
  const int tid = threadIdx.x;
  const int lane = tid & 63, wid = tid >> 6;
  const int row0 = blockIdx.y * 128, col0 = blockIdx.x * 128;
  const int wr = (wid >> 1) * 64, wc = (wid & 1) * 64;
  const int fr = lane & 15;            // fragment row(A)/col(B,C)
  const int kq = (lane >> 4) * 8;      // k-base within BK=32

  f32x4 acc[4][4];
#pragma unroll
  for (int m = 0; m < 4; ++m)
#pragma unroll
    for (int n = 0; n < 4; ++n) acc[m][n] = (f32x4){0.f, 0.f, 0.f, 0.f};

  // staging: 8 segments of 16 rows; wave w owns segs 2w, 2w+1; lane covers
  // row = s*16 + lane/4, k = (lane&3)*8  (LDS linear: dst = base + lane*16B)
  const int srow = (lane >> 2);
  const int skk = (lane & 3) * 8;

  for (int k0 = 0; k0 < K; k0 += 32) {
#pragma unroll
    for (int j = 0; j < 2; ++j) {
      const int s = wid * 2 + j;
      const int r = s * 16 + srow;
      const ushort_t* ga = A + (size_t)(row0 + r) * K + k0 + skk;
      const ushort_t* gb = B + (size_t)(col0 + r) * K + k0 + skk;
      __builtin_amdgcn_global_load_lds(
          (const __attribute__((address_space(1))) unsigned int*)ga,
          (__attribute__((address_space(3))) unsigned int*)(As + s * 512), 16, 0, 0);
      __builtin_amdgcn_global_load_lds(
          (const __attribute__((address_space(1))) unsigned int*)gb,
          (__attribute__((address_space(3))) unsigned int*)(Bs + s * 512), 16, 0, 0);
    }
    __syncthreads();
    short8_t av[4], bv[4];
#pragma unroll
    for (int m = 0; m < 4; ++m)
      av[m] = *(const short8_t*)(As + (wr + m * 16 + fr) * 32 + kq);
#pragma unroll
    for (int n = 0; n < 4; ++n)
      bv[n] = *(const short8_t*)(Bs + (wc + n * 16 + fr) * 32 + kq);
#pragma unroll
    for (int m = 0; m < 4; ++m)
#pragma unroll
      for (int n = 0; n < 4; ++n)
        acc[m][n] = __builtin_amdgcn_mfma_f32_16x16x32_bf16(av[m], bv[n],
                                                            acc[m][n], 0, 0, 0);
    __syncthreads();
  }

  // epilogue: C/D layout col=lane&15, row=(lane>>4)*4+reg  [m89-verified]
#pragma unroll
  for (int m = 0; m < 4; ++m) {
    const int r = row0 + wr + m * 16 + (lane >> 4) * 4;
#pragma unroll
    for (int n = 0; n < 4; ++n) {
      const int col = col0 + wc + n * 16 + fr;
      if (col < Nr) {
        const float bv_ = bias[col];
#pragma unroll
        for (int j = 0; j < 4; ++j)
          C[(size_t)(r + j) * Nr + col] = acc[m][n][j] + bv_;
      }
    }
  }
}

// ---------------- causal depthwise conv (K=4) + silu ----------------
__global__ __launch_bounds__(256)
void conv_silu(const float* __restrict__ proj, const float* __restrict__ cw,
               float* __restrict__ conv) {
  const int idx = blockIdx.x * 256 + threadIdx.x;
  if (idx >= Tt * CONVDc) return;
  const int ch = idx % CONVDc;
  const int t  = idx / CONVDc;
  const int s  = t & (Ss - 1);
  const float4 w = *(const float4*)&cw[ch << 2];
  const float* col = proj + (size_t)t * PROJc + INTERc + ch;
  float acc;
  if (s >= 3) {
    acc = col[-(ptrdiff_t)3*PROJc]*w.x + col[-(ptrdiff_t)2*PROJc]*w.y
        + col[-(ptrdiff_t)PROJc]*w.z + col[0]*w.w;
  } else {
    acc = col[0]*w.w;
    if (s >= 1) acc += col[-(ptrdiff_t)PROJc]*w.z;
    if (s >= 2) acc += col[-(ptrdiff_t)2*PROJc]*w.y;
  }
  conv[idx] = acc / (1.f + __expf(-acc));
}

// ---------------- dt softplus + A*dt ----------------
__global__ __launch_bounds__(256)
void dt_kernel(const float* __restrict__ proj, const float* __restrict__ dt_bias,
               const float* __restrict__ A_log, float* __restrict__ dtv,
               float* __restrict__ adt) {
  const int idx = blockIdx.x * 256 + threadIdx.x;   // T*H
  const int hh = idx & (Hh - 1);
  const int t  = idx >> 5;
  float xv = proj[(size_t)t * PROJc + INTERc + CONVDc + hh] + dt_bias[hh];
  float sp = (xv > 20.f) ? xv : log1pf(__expf(xv));
  dtv[idx] = sp;
  adt[idx] = -__expf(A_log[hh]) * sp;
}

// ---------------- per-(b,c,h) inclusive scan of A*dt ----------------
__global__ __launch_bounds__(256)
void scan_kernel(const float* __restrict__ adt, const float* __restrict__ dtv,
                 float* __restrict__ acumb, float* __restrict__ dtc) {
  const int g = blockIdx.x;          // bc*Hh + h,  512 total
  const int h  = g & (Hh - 1);
  const int bc = g >> 5;
  const int b = bc >> 3, c = bc & 7;
  const int tid = threadIdx.x;
  const int lane = tid & 63, wv = tid >> 6;
  __shared__ float wsum[4];
  const int tg = b * Ss + c * CSc;
  float v  = adt[(size_t)(tg + tid) * Hh + h];
  float dv = dtv[(size_t)(tg + tid) * Hh + h];
#pragma unroll
  for (int off = 1; off < 64; off <<= 1) {
    float u = __shfl_up(v, off);
    if (lane >= off) v += u;
  }
  if (lane == 63) wsum[wv] = v;
  __syncthreads();
  float offacc = 0.f;
  for (int w = 0; w < wv; ++w) offacc += wsum[w];
  acumb[(size_t)g * CSc + tid] = v + offacc;
  dtc[(size_t)g * CSc + tid] = dv;
}

// ---------------- B/C transpose to [b][n][s] ----------------
__global__ __launch_bounds__(256)
void bc_transpose(const float* __restrict__ conv, float* __restrict__ Bt,
                  float* __restrict__ Ct) {
  const int idx = blockIdx.x * 256 + threadIdx.x;   // Bb*Nn*Ss
  const int s = idx & (Ss - 1);
  const int n = (idx >> 11) & (Nn - 1);
  const int b = idx >> 18;
  const size_t src = (size_t)(b * Ss + s) * CONVDc + INTERc;
  Bt[idx] = conv[src + n];
  Ct[idx] = conv[src + Nn + n];
}

// ---------------- G (transposed): Gt[bc][s][l] = sum_n C[l][n]*B[s][n], s<=l ----------------
__global__ __launch_bounds__(256)
void g_kernel(const float* __restrict__ Bt, const float* __restrict__ Ct,
              float* __restrict__ Gt) {
  const int bc = blockIdx.z;           // 0..15
  const int b = bc >> 3;
  const int c = bc & 7;
  const int l = blockIdx.y * 64 + (threadIdx.x & 63);
  const int s = blockIdx.x * 4 + (threadIdx.x >> 6);
  if (s > l) return;
  const int t0 = c * CSc;
  const float* cp = Ct + (size_t)b * Nn * Ss + t0 + l;
  const float* bp = Bt + (size_t)b * Nn * Ss + t0 + s;
  float acc = 0.f;
#pragma unroll 4
  for (int n = 0; n < Nn; ++n) acc += cp[(size_t)n * Ss] * bp[(size_t)n * Ss];
  Gt[((size_t)bc * CSc + s) * CSc + l] = acc;
}

#define ACC16(W, PTR)                                                          \
  {                                                                            \
    const float4* _p = (const float4*)(PTR);                                   \
    float4 _a = _p[0], _b = _p[1], _c = _p[2], _d = _p[3];                     \
    const float _w = (W);                                                      \
    acc[0] += _w*_a.x;  acc[1] += _w*_a.y;  acc[2] += _w*_a.z;  acc[3] += _w*_a.w; \
    acc[4] += _w*_b.x;  acc[5] += _w*_b.y;  acc[6] += _w*_b.z;  acc[7] += _w*_b.w; \
    acc[8] += _w*_c.x;  acc[9] += _w*_c.y;  acc[10]+= _w*_c.z;  acc[11]+= _w*_c.w; \
    acc[12]+= _w*_d.x;  acc[13]+= _w*_d.y;  acc[14]+= _w*_d.z;  acc[15]+= _w*_d.w; \
  }

// ---------------- SSD intra-chunk: Y_diag + D + chunk-local state ----------------
__global__ __launch_bounds__(256)
void ssd_intra(const float* __restrict__ conv, const float* __restrict__ acumb,
               const float* __restrict__ dtc, const float* __restrict__ Gt,
               const float* __restrict__ Dp, float* __restrict__ Y,
               float* __restrict__ S) {
  const int blk = blockIdx.x;          // 2048 = 2*8*32*4
  const int pb = blk & 3;
  const int h  = (blk >> 2) & 31;
  const int c  = (blk >> 7) & 7;
  const int b  = blk >> 10;
  const int p0 = pb * 16;
  const int bc = b * NCc + c;
  const int tg = b * Ss + c * CSc;
  const int tid = threadIdx.x;

  __shared__ float hr[CSc][16];      // raw h tile
  __shared__ float acs[CSc];
  __shared__ float dts[CSc];
  __shared__ float wdec[CSc];

  const float Dh = Dp[h];
  {
    const size_t base = (size_t)(bc * Hh + h) * CSc;
    acs[tid] = acumb[base + tid];
    dts[tid] = dtc[base + tid];
  }
  for (int i = tid; i < CSc * 16; i += 256) {
    const int l = i >> 4, pp = i & 15;
    hr[l][pp] = conv[(size_t)(tg + l) * CONVDc + h * Pp + p0 + pp];
  }
  __syncthreads();
  const float atot = acs[CSc - 1];
  wdec[tid] = __expf(atot - acs[tid]) * dts[tid];
  __syncthreads();

  // ---- Y_diag + D for row l = tid ----
  {
    const int l = tid;
    const float al = acs[l];
    float acc[16];
#pragma unroll
    for (int q = 0; q < 16; ++q) acc[q] = 0.f;
    const float* gp = Gt + (size_t)bc * CSc * CSc + l;
    for (int s = 0; s <= l; ++s) {
      float w = gp[(size_t)s * CSc] * __expf(al - acs[s]) * dts[s];
      ACC16(w, &hr[s][0]);
    }
    ACC16(Dh, &hr[l][0]);
    float* yp = Y + (size_t)(tg + l) * INTERc + h * Pp + p0;
    ((float4*)yp)[0] = make_float4(acc[0], acc[1], acc[2], acc[3]);
    ((float4*)yp)[1] = make_float4(acc[4], acc[5], acc[6], acc[7]);
    ((float4*)yp)[2] = make_float4(acc[8], acc[9], acc[10], acc[11]);
    ((float4*)yp)[3] = make_float4(acc[12], acc[13], acc[14], acc[15]);
  }

  // ---- chunk-local state: S[p][n] = sum_l wdec[l]*hraw[l][p]*B[l][n] ----
  {
    const int pp = tid >> 4, ni = tid & 15;
    float st[8];
#pragma unroll
    for (int i = 0; i < 8; ++i) st[i] = 0.f;
    const float* bbase = conv + (size_t)tg * CONVDc + INTERc + ni;
    for (int lq = 0; lq < CSc; ++lq) {
      const float wl = wdec[lq] * hr[lq][pp];
      const float* bp = bbase + (size_t)lq * CONVDc;
#pragma unroll
      for (int i = 0; i < 8; ++i) st[i] += wl * bp[16 * i];
    }
    float* sp = S + (((size_t)bc * Hh + h) * Pp + p0 + pp) * Nn + ni;
#pragma unroll
    for (int i = 0; i < 8; ++i) sp[16 * i] = st[i];
  }
}

// ---------------- inter-chunk state recurrence (8 steps, elementwise) ----------------
__global__ __launch_bounds__(256)
void state_combine(const float* __restrict__ S, const float* __restrict__ acumb,
                   float* __restrict__ R) {
  const int idx = blockIdx.x * 256 + threadIdx.x;   // Bb*Hh*Pp*Nn = 524288
  const int n = idx & 127;
  const int p = (idx >> 7) & 63;
  const int h = (idx >> 13) & 31;
  const int b = idx >> 18;
  float r = 0.f;
  for (int c = 0; c < NCc; ++c) {
    const int bc = b * NCc + c;
    const size_t off = (((size_t)bc * Hh + h) * Pp + p) * Nn + n;
    R[off] = r;                                     // incoming state for chunk c
    const float atot = acumb[((size_t)bc * Hh + h) * CSc + CSc - 1];
    r = r * __expf(atot) + S[off];
  }
}

// ---------------- SSD off-diagonal: Y += exp(acum)*C·R ----------------
__global__ __launch_bounds__(256)
void ssd_off(const float* __restrict__ Ct, const float* __restrict__ acumb,
             const float* __restrict__ R, float* __restrict__ Y) {
  const int blk = blockIdx.x;          // 2048 = 2*8*32*4
  const int pb = blk & 3;
  const int h  = (blk >> 2) & 31;
  const int c  = (blk >> 7) & 7;
  const int b  = blk >> 10;
  const int p0 = pb * 16;
  const int bc = b * NCc + c;
  const int tg = b * Ss + c * CSc;
  const int tid = threadIdx.x;

  __shared__ float stateT[Nn][20];   // [n][pp], padded
  {
    const size_t rbase = (((size_t)bc * Hh + h) * Pp + p0) * Nn;
    for (int i = tid; i < Nn * 16; i += 256) {
      const int pp = i >> 7, n = i & 127;
      stateT[n][pp] = R[rbase + (size_t)pp * Nn + n];
    }
  }
  __syncthreads();
  const int l = tid;
  const float el = __expf(acumb[((size_t)bc * Hh + h) * CSc + l]);
  float acc[16];
#pragma unroll
  for (int q = 0; q < 16; ++q) acc[q] = 0.f;
  const float* cp = Ct + (size_t)b * Nn * Ss + c * CSc + l;
#pragma unroll 4
  for (int n = 0; n < Nn; ++n) {
    float cv = cp[(size_t)n * Ss];
    ACC16(cv, &stateT[n][0]);
  }
  float* yp = Y + (size_t)(tg + l) * INTERc + h * Pp + p0;
  float4 y0 = ((float4*)yp)[0], y1 = ((float4*)yp)[1];
  float4 y2 = ((float4*)yp)[2], y3 = ((float4*)yp)[3];
  ((float4*)yp)[0] = make_float4(y0.x + el*acc[0],  y0.y + el*acc[1],  y0.z + el*acc[2],  y0.w + el*acc[3]);
  ((float4*)yp)[1] = make_float4(y1.x + el*acc[4],  y1.y + el*acc[5],  y1.z + el*acc[6],  y1.w + el*acc[7]);
  ((float4*)yp)[2] = make_float4(y2.x + el*acc[8],  y2.y + el*acc[9],  y2.z + el*acc[10], y2.w + el*acc[11]);
  ((float4*)yp)[3] = make_float4(y3.x + el*acc[12], y3.y + el*acc[13], y3.z + el*acc[14], y3.w + el*acc[15]);
}

// ---------------- gate * silu + RMSNorm -> bf16 ----------------
__global__ __launch_bounds__(256)
void gate_norm(const float* __restrict__ Y, const float* __restrict__ proj,
               const float* __restrict__ nw, ushort_t* __restrict__ g) {
  const int t = blockIdx.x;
  const int tid = threadIdx.x;
  const int lane = tid & 63, wv = tid >> 6;
  __shared__ float ws4[4];
  const float* yp = Y + (size_t)t * INTERc;
  const float* gp = proj + (size_t)t * PROJc;
  float vals[8];
  float ss = 0.f;
#pragma unroll
  for (int i = 0; i < 8; ++i) {
    const int cix = tid + (i << 8);
    float yv = yp[cix];
    float gv = gp[cix];
    float vv = yv * (gv / (1.f + __expf(-gv)));
    vals[i] = vv;
    ss += vv * vv;
  }
#pragma unroll
  for (int off = 32; off > 0; off >>= 1) ss += __shfl_xor(ss, off);
  if (lane == 0) ws4[wv] = ss;
  __syncthreads();
  const float tot = ws4[0] + ws4[1] + ws4[2] + ws4[3];
  const float sc = rsqrtf(tot * (1.f / INTERc) + 1e-5f);
  ushort_t* go = g + (size_t)t * INTERc;
#pragma unroll
  for (int i = 0; i < 8; ++i) {
    const int cix = tid + (i << 8);
    go[cix] = f2b_rtn(vals[i] * sc * nw[cix]);
  }
}

extern "C" void kernel_launch(void* const* d_in, const int* in_sizes, int n_in,
                              void* d_out, int out_size, void* d_ws, size_t ws_size,
                              hipStream_t stream) {
  (void)in_sizes; (void)n_in; (void)out_size; (void)ws_size;
  const float* x       = (const float*)d_in[0];
  const float* W_in    = (const float*)d_in[1];
  const float* b_in    = (const float*)d_in[2];
  const float* conv_w  = (const float*)d_in[3];
  const float* dt_bias = (const float*)d_in[4];
  const float* A_log   = (const float*)d_in[5];
  const float* Dp      = (const float*)d_in[6];
  const float* norm_w  = (const float*)d_in[7];
  const float* W_out   = (const float*)d_in[8];
  const float* b_out   = (const float*)d_in[9];
  float* out = (float*)d_out;

  float* proj  = (float*)d_ws;
  float* conv  = proj  + (size_t)Tt * PROJc;
  float* dtv   = conv  + (size_t)Tt * CONVDc;
  float* adt   = dtv   + (size_t)Tt * Hh;
  float* Bt    = adt   + (size_t)Tt * Hh;
  float* Ct    = Bt    + (size_t)Bb * Nn * Ss;
  float* Gt    = Ct    + (size_t)Bb * Nn * Ss;
  float* acumb = Gt    + (size_t)Bb * NCc * CSc * CSc;
  float* dtc   = acumb + (size_t)Bb * NCc * Hh * CSc;
  float* Sbuf  = dtc   + (size_t)Bb * NCc * Hh * CSc;
  float* Roff  = Sbuf  + (size_t)Bb * NCc * Hh * Pp * Nn;
  float* Ybuf  = Roff  + (size_t)Bb * NCc * Hh * Pp * Nn;

  // bf16 overlays on regions that are dead at their use time (stream-ordered):
  //  xb  -> Sbuf  (read @GEMM1; Sbuf first written @ssd_intra)
  //  Wib -> Roff  (read @GEMM1; Roff first written @state_combine)  [padded 4480 rows]
  //  Wob -> Gt    (converted AFTER ssd_intra's last Gt read; == Gt bytes exactly)
  //  gbb -> conv  (written @gate_norm, after ssd_intra's last conv read)
  ushort_t* xb  = (ushort_t*)Sbuf;
  ushort_t* Wib = (ushort_t*)Roff;
  ushort_t* Wob = (ushort_t*)Gt;
  ushort_t* gbb = (ushort_t*)conv;

  // 0. fp32->bf16 conversions for GEMM1
  f2b_kernel<<<(Tt * HIDc / 8 + 255) / 256, 256, 0, stream>>>(x, xb, Tt * HIDc / 8);
  f2b_kernel<<<(PROJc * HIDc / 8 + 255) / 256, 256, 0, stream>>>(
      W_in, Wib, PROJc * HIDc / 8);
  // 1. proj = x @ W_in^T + b_in  (bf16 MFMA)
  gemm_bf16<<<dim3(PROJ_PAD / 128, Tt / 128), 256, 0, stream>>>(
      xb, Wib, b_in, proj, Tt, PROJc, HIDc);
  // 2. conv + silu
  conv_silu<<<(Tt * CONVDc) / 256, 256, 0, stream>>>(proj, conv_w, conv);
  // 3. dt
  dt_kernel<<<(Tt * Hh) / 256, 256, 0, stream>>>(proj, dt_bias, A_log, dtv, adt);
  // 4. chunk-local scan of A*dt
  scan_kernel<<<Bb * NCc * Hh, 256, 0, stream>>>(adt, dtv, acumb, dtc);
  // 5. B/C transpose
  bc_transpose<<<(Bb * Nn * Ss) / 256, 256, 0, stream>>>(conv, Bt, Ct);
  // 6. G matrix (transposed storage, lower tri only)
  g_kernel<<<dim3(64, 4, 16), 256, 0, stream>>>(Bt, Ct, Gt);
  // 7. SSD intra-chunk (Y_diag + D + chunk states)
  ssd_intra<<<Bb * NCc * Hh * 4, 256, 0, stream>>>(conv, acumb, dtc, Gt, Dp,
                                                   Ybuf, Sbuf);
  // 8. inter-chunk recurrence
  state_combine<<<(Bb * Hh * Pp * Nn) / 256, 256, 0, stream>>>(Sbuf, acumb, Roff);
  // 9. SSD off-diagonal
  ssd_off<<<Bb * NCc * Hh * 4, 256, 0, stream>>>(Ct, acumb, Roff, Ybuf);
  // 10. W_out -> bf16 (Gt dead after step 7)
  f2b_kernel<<<(HIDc * INTERc / 8 + 255) / 256, 256, 0, stream>>>(
      W_out, Wob, HIDc * INTERc / 8);
  // 11. gate + RMSNorm -> bf16 (conv dead after step 7)
  gate_norm<<<Tt, 256, 0, stream>>>(Ybuf, proj, norm_w, gbb);
  // 12. out = g @ W_out^T + b_out  (bf16 MFMA)
  gemm_bf16<<<dim3(HIDc / 128, Tt / 128), 256, 0, stream>>>(
      gbb, Wob, b_out, out, Tt, HIDc, INTERc);
}

// Round 5
// 399.406 us; speedup vs baseline: 5.0024x; 1.3037x over previous
//
#include <hip/hip_runtime.h>
#include <math.h>

#define Hh     32
#define Pp     64
#define HIDc   1024
#define Nn     128
#define CSc    256
#define INTERc 2048
#define CONVDc 2304
#define PROJc  4384
#define Bb     2
#define Ss     2048
#define Tt     4096
#define NCc    8
#define PROJ_PAD 4480   // PROJc padded up to multiple of 128 for B-staging

typedef __attribute__((ext_vector_type(8))) short short8_t;
typedef __attribute__((ext_vector_type(4))) float f32x4;
typedef unsigned short ushort_t;

__device__ __forceinline__ ushort_t f2b_rtn(float f) {
  unsigned u = __float_as_uint(f);
  unsigned lsb = (u >> 16) & 1u;
  u += 0x7fffu + lsb;
  return (ushort_t)(u >> 16);
}
__device__ __forceinline__ float b2f(ushort_t u) {
  return __uint_as_float(((unsigned)u) << 16);
}

// ---------------- fp32 -> bf16 (RTN), 8 elems/thread ----------------
__global__ __launch_bounds__(256)
void f2b_kernel(const float* __restrict__ in, ushort_t* __restrict__ out, int n8) {
  const int i = blockIdx.x * 256 + threadIdx.x;
  if (i >= n8) return;
  const float4* ip = (const float4*)in;
  float4 a = ip[2 * i], b = ip[2 * i + 1];
  union { short8_t v; ushort_t h[8]; } u;
  u.h[0] = f2b_rtn(a.x); u.h[1] = f2b_rtn(a.y);
  u.h[2] = f2b_rtn(a.z); u.h[3] = f2b_rtn(a.w);
  u.h[4] = f2b_rtn(b.x); u.h[5] = f2b_rtn(b.y);
  u.h[6] = f2b_rtn(b.z); u.h[7] = f2b_rtn(b.w);
  ((short8_t*)out)[i] = u.v;
}

// ---------------- bf16 MFMA GEMM: C[M,Nr] = A[M,K] * B[Npad,K]^T + bias ----------------
__global__ __launch_bounds__(256)
void gemm_bf16(const ushort_t* __restrict__ A, const ushort_t* __restrict__ B,
               const float* __restrict__ bias, float* __restrict__ C,
               int M, int Nr, int K) {
  __shared__ ushort_t As[128 * 32];
  __shared__ ushort_t Bs[128 * 32];
  const int tid = threadIdx.x;
  const int lane = tid & 63, wid = tid >> 6;
  const int row0 = blockIdx.y * 128, col0 = blockIdx.x * 128;
  const int wr = (wid >> 1) * 64, wc = (wid & 1) * 64;
  const int fr = lane & 15;            // fragment row(A)/col(B,C)
  const int kq = (lane >> 4) * 8;      // k-base within BK=32

  f32x4 acc[4][4];
#pragma unroll
  for (int m = 0; m < 4; ++m)
#pragma unroll
    for (int n = 0; n < 4; ++n) acc[m][n] = (f32x4){0.f, 0.f, 0.f, 0.f};

  const int srow = (lane >> 2);
  const int skk = (lane & 3) * 8;

  for (int k0 = 0; k0 < K; k0 += 32) {
#pragma unroll
    for (int j = 0; j < 2; ++j) {
      const int s = wid * 2 + j;
      const int r = s * 16 + srow;
      const ushort_t* ga = A + (size_t)(row0 + r) * K + k0 + skk;
      const ushort_t* gb = B + (size_t)(col0 + r) * K + k0 + skk;
      __builtin_amdgcn_global_load_lds(
          (const __attribute__((address_space(1))) unsigned int*)ga,
          (__attribute__((address_space(3))) unsigned int*)(As + s * 512), 16, 0, 0);
      __builtin_amdgcn_global_load_lds(
          (const __attribute__((address_space(1))) unsigned int*)gb,
          (__attribute__((address_space(3))) unsigned int*)(Bs + s * 512), 16, 0, 0);
    }
    __syncthreads();
    short8_t av[4], bv[4];
#pragma unroll
    for (int m = 0; m < 4; ++m)
      av[m] = *(const short8_t*)(As + (wr + m * 16 + fr) * 32 + kq);
#pragma unroll
    for (int n = 0; n < 4; ++n)
      bv[n] = *(const short8_t*)(Bs + (wc + n * 16 + fr) * 32 + kq);
#pragma unroll
    for (int m = 0; m < 4; ++m)
#pragma unroll
      for (int n = 0; n < 4; ++n)
        acc[m][n] = __builtin_amdgcn_mfma_f32_16x16x32_bf16(av[m], bv[n],
                                                            acc[m][n], 0, 0, 0);
    __syncthreads();
  }

#pragma unroll
  for (int m = 0; m < 4; ++m) {
    const int r = row0 + wr + m * 16 + (lane >> 4) * 4;
#pragma unroll
    for (int n = 0; n < 4; ++n) {
      const int col = col0 + wc + n * 16 + fr;
      if (col < Nr) {
        const float bv_ = bias[col];
#pragma unroll
        for (int j = 0; j < 4; ++j)
          C[(size_t)(r + j) * Nr + col] = acc[m][n][j] + bv_;
      }
    }
  }
}

// ---------------- causal depthwise conv (K=4) + silu ----------------
__global__ __launch_bounds__(256)
void conv_silu(const float* __restrict__ proj, const float* __restrict__ cw,
               float* __restrict__ conv) {
  const int idx = blockIdx.x * 256 + threadIdx.x;
  if (idx >= Tt * CONVDc) return;
  const int ch = idx % CONVDc;
  const int t  = idx / CONVDc;
  const int s  = t & (Ss - 1);
  const float4 w = *(const float4*)&cw[ch << 2];
  const float* col = proj + (size_t)t * PROJc + INTERc + ch;
  float acc;
  if (s >= 3) {
    acc = col[-(ptrdiff_t)3*PROJc]*w.x + col[-(ptrdiff_t)2*PROJc]*w.y
        + col[-(ptrdiff_t)PROJc]*w.z + col[0]*w.w;
  } else {
    acc = col[0]*w.w;
    if (s >= 1) acc += col[-(ptrdiff_t)PROJc]*w.z;
    if (s >= 2) acc += col[-(ptrdiff_t)2*PROJc]*w.y;
  }
  conv[idx] = acc / (1.f + __expf(-acc));
}

// ---------------- dt softplus + A*dt ----------------
__global__ __launch_bounds__(256)
void dt_kernel(const float* __restrict__ proj, const float* __restrict__ dt_bias,
               const float* __restrict__ A_log, float* __restrict__ dtv,
               float* __restrict__ adt) {
  const int idx = blockIdx.x * 256 + threadIdx.x;   // T*H
  const int hh = idx & (Hh - 1);
  const int t  = idx >> 5;
  float xv = proj[(size_t)t * PROJc + INTERc + CONVDc + hh] + dt_bias[hh];
  float sp = (xv > 20.f) ? xv : log1pf(__expf(xv));
  dtv[idx] = sp;
  adt[idx] = -__expf(A_log[hh]) * sp;
}

// ---------------- per-(b,c,h) inclusive scan of A*dt ----------------
__global__ __launch_bounds__(256)
void scan_kernel(const float* __restrict__ adt, const float* __restrict__ dtv,
                 float* __restrict__ acumb, float* __restrict__ dtc) {
  const int g = blockIdx.x;          // bc*Hh + h,  512 total
  const int h  = g & (Hh - 1);
  const int bc = g >> 5;
  const int b = bc >> 3, c = bc & 7;
  const int tid = threadIdx.x;
  const int lane = tid & 63, wv = tid >> 6;
  __shared__ float wsum[4];
  const int tg = b * Ss + c * CSc;
  float v  = adt[(size_t)(tg + tid) * Hh + h];
  float dv = dtv[(size_t)(tg + tid) * Hh + h];
#pragma unroll
  for (int off = 1; off < 64; off <<= 1) {
    float u = __shfl_up(v, off);
    if (lane >= off) v += u;
  }
  if (lane == 63) wsum[wv] = v;
  __syncthreads();
  float offacc = 0.f;
  for (int w = 0; w < wv; ++w) offacc += wsum[w];
  acumb[(size_t)g * CSc + tid] = v + offacc;
  dtc[(size_t)g * CSc + tid] = dv;
}

// ---------------- B/C transpose to [b][n][s] ----------------
__global__ __launch_bounds__(256)
void bc_transpose(const float* __restrict__ conv, float* __restrict__ Bt,
                  float* __restrict__ Ct) {
  const int idx = blockIdx.x * 256 + threadIdx.x;   // Bb*Nn*Ss
  const int s = idx & (Ss - 1);
  const int n = (idx >> 11) & (Nn - 1);
  const int b = idx >> 18;
  const size_t src = (size_t)(b * Ss + s) * CONVDc + INTERc;
  Bt[idx] = conv[src + n];
  Ct[idx] = conv[src + Nn + n];
}

// ---------------- G (transposed): Gt[bc][s][l] = sum_n C[l][n]*B[s][n], s<=l ----------------
__global__ __launch_bounds__(256)
void g_kernel(const float* __restrict__ Bt, const float* __restrict__ Ct,
              float* __restrict__ Gt) {
  const int bc = blockIdx.z;           // 0..15
  const int b = bc >> 3;
  const int c = bc & 7;
  const int l = blockIdx.y * 64 + (threadIdx.x & 63);
  const int s = blockIdx.x * 4 + (threadIdx.x >> 6);
  if (s > l) return;
  const int t0 = c * CSc;
  const float* cp = Ct + (size_t)b * Nn * Ss + t0 + l;
  const float* bp = Bt + (size_t)b * Nn * Ss + t0 + s;
  float acc = 0.f;
#pragma unroll 4
  for (int n = 0; n < Nn; ++n) acc += cp[(size_t)n * Ss] * bp[(size_t)n * Ss];
  Gt[((size_t)bc * CSc + s) * CSc + l] = acc;
}

#define ACC16(W, PTR)                                                          \
  {                                                                            \
    const float4* _p = (const float4*)(PTR);                                   \
    float4 _a = _p[0], _b = _p[1], _c = _p[2], _d = _p[3];                     \
    const float _w = (W);                                                      \
    acc[0] += _w*_a.x;  acc[1] += _w*_a.y;  acc[2] += _w*_a.z;  acc[3] += _w*_a.w; \
    acc[4] += _w*_b.x;  acc[5] += _w*_b.y;  acc[6] += _w*_b.z;  acc[7] += _w*_b.w; \
    acc[8] += _w*_c.x;  acc[9] += _w*_c.y;  acc[10]+= _w*_c.z;  acc[11]+= _w*_c.w; \
    acc[12]+= _w*_d.x;  acc[13]+= _w*_d.y;  acc[14]+= _w*_d.z;  acc[15]+= _w*_d.w; \
  }

// ---------------- SSD intra-chunk via MFMA: Y_diag + D + chunk-local state ----
// one block per (b,c,h); 4 waves.
//  Y_diag[l][p] = sum_{s<=l} W[l][s]*h[s][p],  W = G*exp(al-as)*dt[s]  (in-reg A-frags)
//  S[p][n]     = sum_l h[l][p]*(wdec[l]*B[l][n])
// h staged once in LDS as bf16 fragment-linear: serves BOTH as B-op (Y) and A-op (S).
__global__ __launch_bounds__(256)
void ssd_intra(const float* __restrict__ conv, const float* __restrict__ acumb,
               const float* __restrict__ dtc, const float* __restrict__ Gt,
               const float* __restrict__ Bt, const float* __restrict__ Dp,
               float* __restrict__ Y, float* __restrict__ S) {
  const int blk = blockIdx.x;          // 512 = Bb*NCc*Hh
  const int h  = blk & 31;
  const int c  = (blk >> 5) & 7;
  const int b  = blk >> 8;
  const int bc = b * NCc + c;
  const int tg = b * Ss + c * CSc;
  const int tid = threadIdx.x;
  const int lane = tid & 63, wid = tid >> 6;
  const int fr = lane & 15, kq = lane >> 4;   // frag row/col, k-subgroup

  __shared__ ushort_t hrF[16384];   // [ks(8)][pb(4)][lane(64)][j(8)] bf16
  __shared__ float acs[CSc];
  __shared__ float dts[CSc];
  __shared__ float wdec[CSc];

  {
    const size_t base = (size_t)(bc * Hh + h) * CSc;
    acs[tid] = acumb[base + tid];
    dts[tid] = dtc[base + tid];
  }
  __syncthreads();
  const float atot = acs[CSc - 1];
  wdec[tid] = __expf(atot - acs[tid]) * dts[tid];

  // stage h tile (raw, post-silu) as bf16 in fragment-linear order
  for (int i = tid; i < CSc * Pp; i += 256) {
    const int l = i >> 6, p = i & 63;
    float v = conv[(size_t)(tg + l) * CONVDc + h * Pp + p];
    const int off = ((l >> 5) * 4 + (p >> 4)) * 512 +
                    ((p & 15) + ((l >> 3) & 3) * 16) * 8 + (l & 7);
    hrF[off] = f2b_rtn(v);
  }
  __syncthreads();

  // ================= GEMM-Y: Y_diag (wave wid owns rows [64*wid, 64*wid+64)) ====
  const int L0 = wid * 64;
  float al[4];
#pragma unroll
  for (int m = 0; m < 4; ++m) al[m] = acs[L0 + m * 16 + fr];

  f32x4 accY[4][4];
#pragma unroll
  for (int m = 0; m < 4; ++m)
#pragma unroll
    for (int n = 0; n < 4; ++n) accY[m][n] = (f32x4){0.f, 0.f, 0.f, 0.f};

  const float* gbase = Gt + (size_t)bc * CSc * CSc;
  const int kslim = 2 * wid + 2;      // triangle: skip K-steps above diagonal
  for (int ks = 0; ks < kslim; ++ks) {
    short8_t bv[4];
#pragma unroll
    for (int pb = 0; pb < 4; ++pb)
      bv[pb] = *(const short8_t*)(hrF + ((ks * 4 + pb) * 64 + lane) * 8);
    const int sb2 = ks * 32 + kq * 8;
    short8_t av[4];
#pragma unroll
    for (int m = 0; m < 4; ++m) {
      const int l = L0 + m * 16 + fr;
      const float alm = al[m];
      union { short8_t v; ushort_t u[8]; } pk;
#pragma unroll
      for (int j = 0; j < 8; ++j) {
        const int s = sb2 + j;
        float g = gbase[(size_t)s * CSc + l];
        float w = g * __expf(alm - acs[s]) * dts[s];
        w = (s <= l) ? w : 0.f;     // mask (discards inf/NaN garbage)
        pk.u[j] = f2b_rtn(w);
      }
      av[m] = pk.v;
    }
#pragma unroll
    for (int m = 0; m < 4; ++m)
#pragma unroll
      for (int pb = 0; pb < 4; ++pb)
        accY[m][pb] = __builtin_amdgcn_mfma_f32_16x16x32_bf16(av[m], bv[pb],
                                                              accY[m][pb], 0, 0, 0);
  }

  // epilogue Y: row l = L0+m*16+kq*4+j, col p = pb*16+fr; add D*h
  const float Dh = Dp[h];
#pragma unroll
  for (int m = 0; m < 4; ++m) {
#pragma unroll
    for (int pb = 0; pb < 4; ++pb) {
      const int p = pb * 16 + fr;
#pragma unroll
      for (int j = 0; j < 4; ++j) {
        const int l = L0 + m * 16 + kq * 4 + j;
        const int off = ((l >> 5) * 4 + pb) * 512 +
                        (fr + ((l >> 3) & 3) * 16) * 8 + (l & 7);
        Y[(size_t)(tg + l) * INTERc + h * Pp + p] =
            accY[m][pb][j] + Dh * b2f(hrF[off]);
      }
    }
  }

  // ================= GEMM-S: S[p][n] (wave wid owns cols [32*wid, 32*wid+32)) ===
  f32x4 accS[4][2];
#pragma unroll
  for (int m = 0; m < 4; ++m)
#pragma unroll
    for (int n = 0; n < 2; ++n) accS[m][n] = (f32x4){0.f, 0.f, 0.f, 0.f};

  const int N0 = wid * 32;
  const float* btb = Bt + (size_t)b * Nn * Ss + c * CSc;
  for (int ks = 0; ks < 8; ++ks) {
    short8_t am[4];
#pragma unroll
    for (int m = 0; m < 4; ++m)
      am[m] = *(const short8_t*)(hrF + ((ks * 4 + m) * 64 + lane) * 8);
    const int l0 = ks * 32 + kq * 8;
    short8_t bn[2];
#pragma unroll
    for (int nf = 0; nf < 2; ++nf) {
      const int n = N0 + nf * 16 + fr;
      const float* bp = btb + (size_t)n * Ss + l0;
      float4 v0 = *(const float4*)bp;
      float4 v1 = *(const float4*)(bp + 4);
      union { short8_t v; ushort_t u[8]; } pk;
      pk.u[0] = f2b_rtn(v0.x * wdec[l0 + 0]);
      pk.u[1] = f2b_rtn(v0.y * wdec[l0 + 1]);
      pk.u[2] = f2b_rtn(v0.z * wdec[l0 + 2]);
      pk.u[3] = f2b_rtn(v0.w * wdec[l0 + 3]);
      pk.u[4] = f2b_rtn(v1.x * wdec[l0 + 4]);
      pk.u[5] = f2b_rtn(v1.y * wdec[l0 + 5]);
      pk.u[6] = f2b_rtn(v1.z * wdec[l0 + 6]);
      pk.u[7] = f2b_rtn(v1.w * wdec[l0 + 7]);
      bn[nf] = pk.v;
    }
#pragma unroll
    for (int m = 0; m < 4; ++m)
#pragma unroll
      for (int nf = 0; nf < 2; ++nf)
        accS[m][nf] = __builtin_amdgcn_mfma_f32_16x16x32_bf16(am[m], bn[nf],
                                                              accS[m][nf], 0, 0, 0);
  }

  // epilogue S: row p = m*16+kq*4+j, col n = N0+nf*16+fr
  float* sp = S + ((size_t)bc * Hh + h) * Pp * Nn;
#pragma unroll
  for (int m = 0; m < 4; ++m)
#pragma unroll
    for (int nf = 0; nf < 2; ++nf) {
      const int n = N0 + nf * 16 + fr;
#pragma unroll
      for (int j = 0; j < 4; ++j)
        sp[(size_t)(m * 16 + kq * 4 + j) * Nn + n] = accS[m][nf][j];
    }
}

// ---------------- inter-chunk state recurrence (8 steps, elementwise) ----------------
__global__ __launch_bounds__(256)
void state_combine(const float* __restrict__ S, const float* __restrict__ acumb,
                   float* __restrict__ R) {
  const int idx = blockIdx.x * 256 + threadIdx.x;   // Bb*Hh*Pp*Nn = 524288
  const int n = idx & 127;
  const int p = (idx >> 7) & 63;
  const int h = (idx >> 13) & 31;
  const int b = idx >> 18;
  float r = 0.f;
  for (int c = 0; c < NCc; ++c) {
    const int bc = b * NCc + c;
    const size_t off = (((size_t)bc * Hh + h) * Pp + p) * Nn + n;
    R[off] = r;                                     // incoming state for chunk c
    const float atot = acumb[((size_t)bc * Hh + h) * CSc + CSc - 1];
    r = r * __expf(atot) + S[off];
  }
}

// ---------------- SSD off-diagonal: Y += exp(acum)*C·R ----------------
__global__ __launch_bounds__(256)
void ssd_off(const float* __restrict__ Ct, const float* __restrict__ acumb,
             const float* __restrict__ R, float* __restrict__ Y) {
  const int blk = blockIdx.x;          // 2048 = 2*8*32*4
  const int pb = blk & 3;
  const int h  = (blk >> 2) & 31;
  const int c  = (blk >> 7) & 7;
  const int b  = blk >> 10;
  const int p0 = pb * 16;
  const int bc = b * NCc + c;
  const int tg = b * Ss + c * CSc;
  const int tid = threadIdx.x;

  __shared__ float stateT[Nn][20];   // [n][pp], padded
  {
    const size_t rbase = (((size_t)bc * Hh + h) * Pp + p0) * Nn;
    for (int i = tid; i < Nn * 16; i += 256) {
      const int pp = i >> 7, n = i & 127;
      stateT[n][pp] = R[rbase + (size_t)pp * Nn + n];
    }
  }
  __syncthreads();
  const int l = tid;
  const float el = __expf(acumb[((size_t)bc * Hh + h) * CSc + l]);
  float acc[16];
#pragma unroll
  for (int q = 0; q < 16; ++q) acc[q] = 0.f;
  const float* cp = Ct + (size_t)b * Nn * Ss + c * CSc + l;
#pragma unroll 4
  for (int n = 0; n < Nn; ++n) {
    float cv = cp[(size_t)n * Ss];
    ACC16(cv, &stateT[n][0]);
  }
  float* yp = Y + (size_t)(tg + l) * INTERc + h * Pp + p0;
  float4 y0 = ((float4*)yp)[0], y1 = ((float4*)yp)[1];
  float4 y2 = ((float4*)yp)[2], y3 = ((float4*)yp)[3];
  ((float4*)yp)[0] = make_float4(y0.x + el*acc[0],  y0.y + el*acc[1],  y0.z + el*acc[2],  y0.w + el*acc[3]);
  ((float4*)yp)[1] = make_float4(y1.x + el*acc[4],  y1.y + el*acc[5],  y1.z + el*acc[6],  y1.w + el*acc[7]);
  ((float4*)yp)[2] = make_float4(y2.x + el*acc[8],  y2.y + el*acc[9],  y2.z + el*acc[10], y2.w + el*acc[11]);
  ((float4*)yp)[3] = make_float4(y3.x + el*acc[12], y3.y + el*acc[13], y3.z + el*acc[14], y3.w + el*acc[15]);
}

// ---------------- gate * silu + RMSNorm -> bf16 ----------------
__global__ __launch_bounds__(256)
void gate_norm(const float* __restrict__ Y, const float* __restrict__ proj,
               const float* __restrict__ nw, ushort_t* __restrict__ g) {
  const int t = blockIdx.x;
  const int tid = threadIdx.x;
  const int lane = tid & 63, wv = tid >> 6;
  __shared__ float ws4[4];
  const float* yp = Y + (size_t)t * INTERc;
  const float* gp = proj + (size_t)t * PROJc;
  float vals[8];
  float ss = 0.f;
#pragma unroll
  for (int i = 0; i < 8; ++i) {
    const int cix = tid + (i << 8);
    float yv = yp[cix];
    float gv = gp[cix];
    float vv = yv * (gv / (1.f + __expf(-gv)));
    vals[i] = vv;
    ss += vv * vv;
  }
#pragma unroll
  for (int off = 32; off > 0; off >>= 1) ss += __shfl_xor(ss, off);
  if (lane == 0) ws4[wv] = ss;
  __syncthreads();
  const float tot = ws4[0] + ws4[1] + ws4[2] + ws4[3];
  const float sc = rsqrtf(tot * (1.f / INTERc) + 1e-5f);
  ushort_t* go = g + (size_t)t * INTERc;
#pragma unroll
  for (int i = 0; i < 8; ++i) {
    const int cix = tid + (i << 8);
    go[cix] = f2b_rtn(vals[i] * sc * nw[cix]);
  }
}

extern "C" void kernel_launch(void* const* d_in, const int* in_sizes, int n_in,
                              void* d_out, int out_size, void* d_ws, size_t ws_size,
                              hipStream_t stream) {
  (void)in_sizes; (void)n_in; (void)out_size; (void)ws_size;
  const float* x       = (const float*)d_in[0];
  const float* W_in    = (const float*)d_in[1];
  const float* b_in    = (const float*)d_in[2];
  const float* conv_w  = (const float*)d_in[3];
  const float* dt_bias = (const float*)d_in[4];
  const float* A_log   = (const float*)d_in[5];
  const float* Dp      = (const float*)d_in[6];
  const float* norm_w  = (const float*)d_in[7];
  const float* W_out   = (const float*)d_in[8];
  const float* b_out   = (const float*)d_in[9];
  float* out = (float*)d_out;

  float* proj  = (float*)d_ws;
  float* conv  = proj  + (size_t)Tt * PROJc;
  float* dtv   = conv  + (size_t)Tt * CONVDc;
  float* adt   = dtv   + (size_t)Tt * Hh;
  float* Bt    = adt   + (size_t)Tt * Hh;
  float* Ct    = Bt    + (size_t)Bb * Nn * Ss;
  float* Gt    = Ct    + (size_t)Bb * Nn * Ss;
  float* acumb = Gt    + (size_t)Bb * NCc * CSc * CSc;
  float* dtc   = acumb + (size_t)Bb * NCc * Hh * CSc;
  float* Sbuf  = dtc   + (size_t)Bb * NCc * Hh * CSc;
  float* Roff  = Sbuf  + (size_t)Bb * NCc * Hh * Pp * Nn;
  float* Ybuf  = Roff  + (size_t)Bb * NCc * Hh * Pp * Nn;

  // bf16 overlays on regions dead at use time (stream-ordered):
  ushort_t* xb  = (ushort_t*)Sbuf;
  ushort_t* Wib = (ushort_t*)Roff;
  ushort_t* Wob = (ushort_t*)Gt;
  ushort_t* gbb = (ushort_t*)conv;

  // 0. fp32->bf16 conversions for GEMM1
  f2b_kernel<<<(Tt * HIDc / 8 + 255) / 256, 256, 0, stream>>>(x, xb, Tt * HIDc / 8);
  f2b_kernel<<<(PROJc * HIDc / 8 + 255) / 256, 256, 0, stream>>>(
      W_in, Wib, PROJc * HIDc / 8);
  // 1. proj = x @ W_in^T + b_in  (bf16 MFMA)
  gemm_bf16<<<dim3(PROJ_PAD / 128, Tt / 128), 256, 0, stream>>>(
      xb, Wib, b_in, proj, Tt, PROJc, HIDc);
  // 2. conv + silu
  conv_silu<<<(Tt * CONVDc) / 256, 256, 0, stream>>>(proj, conv_w, conv);
  // 3. dt
  dt_kernel<<<(Tt * Hh) / 256, 256, 0, stream>>>(proj, dt_bias, A_log, dtv, adt);
  // 4. chunk-local scan of A*dt
  scan_kernel<<<Bb * NCc * Hh, 256, 0, stream>>>(adt, dtv, acumb, dtc);
  // 5. B/C transpose
  bc_transpose<<<(Bb * Nn * Ss) / 256, 256, 0, stream>>>(conv, Bt, Ct);
  // 6. G matrix (transposed storage, lower tri only)
  g_kernel<<<dim3(64, 4, 16), 256, 0, stream>>>(Bt, Ct, Gt);
  // 7. SSD intra-chunk via MFMA (Y_diag + D + chunk states)
  ssd_intra<<<Bb * NCc * Hh, 256, 0, stream>>>(conv, acumb, dtc, Gt, Bt, Dp,
                                               Ybuf, Sbuf);
  // 8. inter-chunk recurrence
  state_combine<<<(Bb * Hh * Pp * Nn) / 256, 256, 0, stream>>>(Sbuf, acumb, Roff);
  // 9. SSD off-diagonal
  ssd_off<<<Bb * NCc * Hh * 4, 256, 0, stream>>>(Ct, acumb, Roff, Ybuf);
  // 10. W_out -> bf16 (Gt dead after step 7)
  f2b_kernel<<<(HIDc * INTERc / 8 + 255) / 256, 256, 0, stream>>>(
      W_out, Wob, HIDc * INTERc / 8);
  // 11. gate + RMSNorm -> bf16 (conv dead after step 7)
  gate_norm<<<Tt, 256, 0, stream>>>(Ybuf, proj, norm_w, gbb);
  // 12. out = g @ W_out^T + b_out  (bf16 MFMA)
  gemm_bf16<<<dim3(HIDc / 128, Tt / 128), 256, 0, stream>>>(
      gbb, Wob, b_out, out, Tt, HIDc, INTERc);
}

// Round 8
// 382.507 us; speedup vs baseline: 5.2235x; 1.0442x over previous
//
#include <hip/hip_runtime.h>
#include <math.h>

#define Hh     32
#define Pp     64
#define HIDc   1024
#define Nn     128
#define CSc    256
#define INTERc 2048
#define CONVDc 2304
#define PROJc  4384
#define Bb     2
#define Ss     2048
#define Tt     4096
#define NCc    8
#define PROJ_PAD 4608   // PROJc padded to multiple of 256 for gemm256 B-staging

typedef __attribute__((ext_vector_type(8))) short short8_t;
typedef __attribute__((ext_vector_type(4))) float f32x4;
typedef unsigned short ushort_t;

__device__ __forceinline__ ushort_t f2b_rtn(float f) {
  unsigned u = __float_as_uint(f);
  unsigned lsb = (u >> 16) & 1u;
  u += 0x7fffu + lsb;
  return (ushort_t)(u >> 16);
}
__device__ __forceinline__ float b2f(ushort_t u) {
  return __uint_as_float(((unsigned)u) << 16);
}

__device__ __forceinline__ int xcd_swz(int bid, int nwg) {
  // bijective XCD swizzle (m204)
  const int q = nwg >> 3, r = nwg & 7;
  const int xcd = bid & 7, loc = bid >> 3;
  return (xcd < r ? xcd * (q + 1) : r * (q + 1) + (xcd - r) * q) + loc;
}

// ---------------- fp32 -> bf16 (RTN), 8 elems/thread ----------------
__global__ __launch_bounds__(256)
void f2b_kernel(const float* __restrict__ in, ushort_t* __restrict__ out, int n8) {
  const int i = blockIdx.x * 256 + threadIdx.x;
  if (i >= n8) return;
  const float4* ip = (const float4*)in;
  float4 a = ip[2 * i], b = ip[2 * i + 1];
  union { short8_t v; ushort_t h[8]; } u;
  u.h[0] = f2b_rtn(a.x); u.h[1] = f2b_rtn(a.y);
  u.h[2] = f2b_rtn(a.z); u.h[3] = f2b_rtn(a.w);
  u.h[4] = f2b_rtn(b.x); u.h[5] = f2b_rtn(b.y);
  u.h[6] = f2b_rtn(b.z); u.h[7] = f2b_rtn(b.w);
  ((short8_t*)out)[i] = u.v;
}

// ============ 256x256 bf16 MFMA GEMM, BK=64, 8 waves, 2-phase dbuf =========
// LDS layout per matrix: row r (0..255) at r*128B; 16B-chunk q stored at
// position q^(r&7)  (conflict-free quarter-wave ds_read_b128).
// Staging: global_load_lds linear dest; SOURCE pre-swizzled per rule #21.
__global__ __launch_bounds__(512, 2)
void gemm256(const ushort_t* __restrict__ A, const ushort_t* __restrict__ B,
             const float* __restrict__ bias, float* __restrict__ C,
             int M, int Nr, int K, int nbx) {
  __shared__ ushort_t lds[2][2][256 * 64];
  int bid = xcd_swz(blockIdx.x, gridDim.x);
  const int bx = bid % nbx, by = bid / nbx;
  const int row0 = by * 256, col0 = bx * 256;
  const int tid = threadIdx.x;
  const int lane = tid & 63, wid = tid >> 6;
  const int wm = wid >> 2, wn = wid & 3;     // 2 x 4 wave grid
  const int fr = lane & 15, kq = lane >> 4;

  // staging source: lane l -> row (l>>3), chunk (l&7)^((l>>3)&7)
  const int srow = lane >> 3;
  const int sq = (lane & 7) ^ ((lane >> 3) & 7);
  const int KT = K >> 6;

  f32x4 acc[8][4];
#pragma unroll
  for (int m = 0; m < 8; ++m)
#pragma unroll
    for (int n = 0; n < 4; ++n) acc[m][n] = (f32x4){0.f, 0.f, 0.f, 0.f};

  auto stage = [&](int buf, int kt) {
    const int k0 = kt << 6;
#pragma unroll
    for (int i = 0; i < 4; ++i) {
      const int g = wid * 4 + i;               // 8-row group 0..31
      const int r = g * 8 + srow;
      const ushort_t* ga = A + (size_t)(row0 + r) * K + k0 + sq * 8;
      const ushort_t* gb = B + (size_t)(col0 + r) * K + k0 + sq * 8;
      __builtin_amdgcn_global_load_lds(
          (const __attribute__((address_space(1))) unsigned int*)ga,
          (__attribute__((address_space(3))) unsigned int*)(&lds[buf][0][0] + g * 512),
          16, 0, 0);
      __builtin_amdgcn_global_load_lds(
          (const __attribute__((address_space(1))) unsigned int*)gb,
          (__attribute__((address_space(3))) unsigned int*)(&lds[buf][1][0] + g * 512),
          16, 0, 0);
    }
  };

  stage(0, 0);
  __syncthreads();
  int cur = 0;
  for (int kt = 0; kt < KT; ++kt) {
    if (kt + 1 < KT) stage(cur ^ 1, kt + 1);   // prefetch BEFORE compute (T3)
    const ushort_t* As = &lds[cur][0][0];
    const ushort_t* Bs = &lds[cur][1][0];
    __builtin_amdgcn_s_setprio(1);
#pragma unroll
    for (int ksub = 0; ksub < 2; ++ksub) {
      const int q = ksub * 4 + kq;
      short8_t av[8], bv[4];
#pragma unroll
      for (int m = 0; m < 8; ++m) {
        const int r = wm * 128 + m * 16 + fr;
        av[m] = *(const short8_t*)(As + r * 64 + (q ^ (r & 7)) * 8);
      }
#pragma unroll
      for (int n = 0; n < 4; ++n) {
        const int r = wn * 64 + n * 16 + fr;
        bv[n] = *(const short8_t*)(Bs + r * 64 + (q ^ (r & 7)) * 8);
      }
#pragma unroll
      for (int m = 0; m < 8; ++m)
#pragma unroll
        for (int n = 0; n < 4; ++n)
          acc[m][n] = __builtin_amdgcn_mfma_f32_16x16x32_bf16(av[m], bv[n],
                                                              acc[m][n], 0, 0, 0);
    }
    __builtin_amdgcn_s_setprio(0);
    __syncthreads();                           // drains vmcnt+lgkmcnt (compiler)
    cur ^= 1;
  }

#pragma unroll
  for (int m = 0; m < 8; ++m) {
    const int r = row0 + wm * 128 + m * 16 + kq * 4;
#pragma unroll
    for (int n = 0; n < 4; ++n) {
      const int col = col0 + wn * 64 + n * 16 + fr;
      if (col < Nr) {
        const float bv_ = bias[col];
#pragma unroll
        for (int j = 0; j < 4; ++j)
          C[(size_t)(r + j) * Nr + col] = acc[m][n][j] + bv_;
      }
    }
  }
}

// ============ 128x128 bf16 MFMA GEMM, BK=32, 2-phase dbuf, swizzled ========
// LDS: row r at r*64B; chunk q (0..3) at position (q + (r>>1)) & 3.
__global__ __launch_bounds__(256)
void gemm_bf16(const ushort_t* __restrict__ A, const ushort_t* __restrict__ B,
               const float* __restrict__ bias, float* __restrict__ C,
               int M, int Nr, int K, int nbx) {
  __shared__ ushort_t lds[2][2][128 * 32];
  int bid = xcd_swz(blockIdx.x, gridDim.x);
  const int bx = bid % nbx, by = bid / nbx;
  const int row0 = by * 128, col0 = bx * 128;
  const int tid = threadIdx.x;
  const int lane = tid & 63, wid = tid >> 6;
  const int wr = (wid >> 1) * 64, wc = (wid & 1) * 64;
  const int fr = lane & 15, kq = lane >> 4;

  // staging source: lane l -> row (l>>2), chunk ((l&3) - ((l>>3)&3)) & 3
  const int srow = lane >> 2;
  const int sq = ((lane & 3) - ((lane >> 3) & 3)) & 3;
  const int KT = K >> 5;

  f32x4 acc[4][4];
#pragma unroll
  for (int m = 0; m < 4; ++m)
#pragma unroll
    for (int n = 0; n < 4; ++n) acc[m][n] = (f32x4){0.f, 0.f, 0.f, 0.f};

  auto stage = [&](int buf, int kt) {
    const int k0 = kt << 5;
#pragma unroll
    for (int j = 0; j < 2; ++j) {
      const int g = wid * 2 + j;               // 16-row group 0..7
      const int r = g * 16 + srow;
      const ushort_t* ga = A + (size_t)(row0 + r) * K + k0 + sq * 8;
      const ushort_t* gb = B + (size_t)(col0 + r) * K + k0 + sq * 8;
      __builtin_amdgcn_global_load_lds(
          (const __attribute__((address_space(1))) unsigned int*)ga,
          (__attribute__((address_space(3))) unsigned int*)(&lds[buf][0][0] + g * 512),
          16, 0, 0);
      __builtin_amdgcn_global_load_lds(
          (const __attribute__((address_space(1))) unsigned int*)gb,
          (__attribute__((address_space(3))) unsigned int*)(&lds[buf][1][0] + g * 512),
          16, 0, 0);
    }
  };

  stage(0, 0);
  __syncthreads();
  int cur = 0;
  for (int kt = 0; kt < KT; ++kt) {
    if (kt + 1 < KT) stage(cur ^ 1, kt + 1);
    const ushort_t* As = &lds[cur][0][0];
    const ushort_t* Bs = &lds[cur][1][0];
    short8_t av[4], bv[4];
#pragma unroll
    for (int m = 0; m < 4; ++m) {
      const int r = wr + m * 16 + fr;
      av[m] = *(const short8_t*)(As + r * 32 + ((kq + ((r >> 1) & 3)) & 3) * 8);
    }
#pragma unroll
    for (int n = 0; n < 4; ++n) {
      const int r = wc + n * 16 + fr;
      bv[n] = *(const short8_t*)(Bs + r * 32 + ((kq + ((r >> 1) & 3)) & 3) * 8);
    }
#pragma unroll
    for (int m = 0; m < 4; ++m)
#pragma unroll
      for (int n = 0; n < 4; ++n)
        acc[m][n] = __builtin_amdgcn_mfma_f32_16x16x32_bf16(av[m], bv[n],
                                                            acc[m][n], 0, 0, 0);
    __syncthreads();
    cur ^= 1;
  }

#pragma unroll
  for (int m = 0; m < 4; ++m) {
    const int r = row0 + wr + m * 16 + kq * 4;
#pragma unroll
    for (int n = 0; n < 4; ++n) {
      const int col = col0 + wc + n * 16 + fr;
      if (col < Nr) {
        const float bv_ = bias[col];
#pragma unroll
        for (int j = 0; j < 4; ++j)
          C[(size_t)(r + j) * Nr + col] = acc[m][n][j] + bv_;
      }
    }
  }
}

// ---------------- causal depthwise conv (K=4) + silu ----------------
__global__ __launch_bounds__(256)
void conv_silu(const float* __restrict__ proj, const float* __restrict__ cw,
               float* __restrict__ conv) {
  const int idx = blockIdx.x * 256 + threadIdx.x;
  if (idx >= Tt * CONVDc) return;
  const int ch = idx % CONVDc;
  const int t  = idx / CONVDc;
  const int s  = t & (Ss - 1);
  const float4 w = *(const float4*)&cw[ch << 2];
  const float* col = proj + (size_t)t * PROJc + INTERc + ch;
  float acc;
  if (s >= 3) {
    acc = col[-(ptrdiff_t)3*PROJc]*w.x + col[-(ptrdiff_t)2*PROJc]*w.y
        + col[-(ptrdiff_t)PROJc]*w.z + col[0]*w.w;
  } else {
    acc = col[0]*w.w;
    if (s >= 1) acc += col[-(ptrdiff_t)PROJc]*w.z;
    if (s >= 2) acc += col[-(ptrdiff_t)2*PROJc]*w.y;
  }
  conv[idx] = acc / (1.f + __expf(-acc));
}

// ---------------- dt softplus + A*dt ----------------
__global__ __launch_bounds__(256)
void dt_kernel(const float* __restrict__ proj, const float* __restrict__ dt_bias,
               const float* __restrict__ A_log, float* __restrict__ dtv,
               float* __restrict__ adt) {
  const int idx = blockIdx.x * 256 + threadIdx.x;   // T*H
  const int hh = idx & (Hh - 1);
  const int t  = idx >> 5;
  float xv = proj[(size_t)t * PROJc + INTERc + CONVDc + hh] + dt_bias[hh];
  float sp = (xv > 20.f) ? xv : log1pf(__expf(xv));
  dtv[idx] = sp;
  adt[idx] = -__expf(A_log[hh]) * sp;
}

// ---------------- per-(b,c,h) inclusive scan of A*dt ----------------
__global__ __launch_bounds__(256)
void scan_kernel(const float* __restrict__ adt, const float* __restrict__ dtv,
                 float* __restrict__ acumb, float* __restrict__ dtc) {
  const int g = blockIdx.x;          // bc*Hh + h,  512 total
  const int h  = g & (Hh - 1);
  const int bc = g >> 5;
  const int b = bc >> 3, c = bc & 7;
  const int tid = threadIdx.x;
  const int lane = tid & 63, wv = tid >> 6;
  __shared__ float wsum[4];
  const int tg = b * Ss + c * CSc;
  float v  = adt[(size_t)(tg + tid) * Hh + h];
  float dv = dtv[(size_t)(tg + tid) * Hh + h];
#pragma unroll
  for (int off = 1; off < 64; off <<= 1) {
    float u = __shfl_up(v, off);
    if (lane >= off) v += u;
  }
  if (lane == 63) wsum[wv] = v;
  __syncthreads();
  float offacc = 0.f;
  for (int w = 0; w < wv; ++w) offacc += wsum[w];
  acumb[(size_t)g * CSc + tid] = v + offacc;
  dtc[(size_t)g * CSc + tid] = dv;
}

// ---------------- B/C transpose to [b][n][s] ----------------
__global__ __launch_bounds__(256)
void bc_transpose(const float* __restrict__ conv, float* __restrict__ Bt,
                  float* __restrict__ Ct) {
  const int idx = blockIdx.x * 256 + threadIdx.x;   // Bb*Nn*Ss
  const int s = idx & (Ss - 1);
  const int n = (idx >> 11) & (Nn - 1);
  const int b = idx >> 18;
  const size_t src = (size_t)(b * Ss + s) * CONVDc + INTERc;
  Bt[idx] = conv[src + n];
  Ct[idx] = conv[src + Nn + n];
}

// ---------------- G (transposed): Gt[bc][s][l] = sum_n C[l][n]*B[s][n], s<=l ----------------
__global__ __launch_bounds__(256)
void g_kernel(const float* __restrict__ Bt, const float* __restrict__ Ct,
              float* __restrict__ Gt) {
  const int bc = blockIdx.z;           // 0..15
  const int b = bc >> 3;
  const int c = bc & 7;
  const int l = blockIdx.y * 64 + (threadIdx.x & 63);
  const int s = blockIdx.x * 4 + (threadIdx.x >> 6);
  if (s > l) return;
  const int t0 = c * CSc;
  const float* cp = Ct + (size_t)b * Nn * Ss + t0 + l;
  const float* bp = Bt + (size_t)b * Nn * Ss + t0 + s;
  float acc = 0.f;
#pragma unroll 4
  for (int n = 0; n < Nn; ++n) acc += cp[(size_t)n * Ss] * bp[(size_t)n * Ss];
  Gt[((size_t)bc * CSc + s) * CSc + l] = acc;
}

#define ACC16(W, PTR)                                                          \
  {                                                                            \
    const float4* _p = (const float4*)(PTR);                                   \
    float4 _a = _p[0], _b = _p[1], _c = _p[2], _d = _p[3];                     \
    const float _w = (W);                                                      \
    acc[0] += _w*_a.x;  acc[1] += _w*_a.y;  acc[2] += _w*_a.z;  acc[3] += _w*_a.w; \
    acc[4] += _w*_b.x;  acc[5] += _w*_b.y;  acc[6] += _w*_b.z;  acc[7] += _w*_b.w; \
    acc[8] += _w*_c.x;  acc[9] += _w*_c.y;  acc[10]+= _w*_c.z;  acc[11]+= _w*_c.w; \
    acc[12]+= _w*_d.x;  acc[13]+= _w*_d.y;  acc[14]+= _w*_d.z;  acc[15]+= _w*_d.w; \
  }

// ---------------- SSD intra-chunk via MFMA: Y_diag + D + chunk-local state ----
__global__ __launch_bounds__(256)
void ssd_intra(const float* __restrict__ conv, const float* __restrict__ acumb,
               const float* __restrict__ dtc, const float* __restrict__ Gt,
               const float* __restrict__ Bt, const float* __restrict__ Dp,
               float* __restrict__ Y, float* __restrict__ S) {
  const int blk = blockIdx.x;          // 512 = Bb*NCc*Hh
  const int h  = blk & 31;
  const int c  = (blk >> 5) & 7;
  const int b  = blk >> 8;
  const int bc = b * NCc + c;
  const int tg = b * Ss + c * CSc;
  const int tid = threadIdx.x;
  const int lane = tid & 63, wid = tid >> 6;
  const int fr = lane & 15, kq = lane >> 4;   // frag row/col, k-subgroup

  __shared__ ushort_t hrF[16384];   // [ks(8)][pb(4)][lane(64)][j(8)] bf16
  __shared__ float acs[CSc];
  __shared__ float dts[CSc];
  __shared__ float wdec[CSc];

  {
    const size_t base = (size_t)(bc * Hh + h) * CSc;
    acs[tid] = acumb[base + tid];
    dts[tid] = dtc[base + tid];
  }
  __syncthreads();
  const float atot = acs[CSc - 1];
  wdec[tid] = __expf(atot - acs[tid]) * dts[tid];

  // stage h tile (raw, post-silu) as bf16 in fragment-linear order
  for (int i = tid; i < CSc * Pp; i += 256) {
    const int l = i >> 6, p = i & 63;
    float v = conv[(size_t)(tg + l) * CONVDc + h * Pp + p];
    const int off = ((l >> 5) * 4 + (p >> 4)) * 512 +
                    ((p & 15) + ((l >> 3) & 3) * 16) * 8 + (l & 7);
    hrF[off] = f2b_rtn(v);
  }
  __syncthreads();

  // ================= GEMM-Y: Y_diag (wave wid owns rows [64*wid, 64*wid+64)) ====
  const int L0 = wid * 64;
  float al[4];
#pragma unroll
  for (int m = 0; m < 4; ++m) al[m] = acs[L0 + m * 16 + fr];

  f32x4 accY[4][4];
#pragma unroll
  for (int m = 0; m < 4; ++m)
#pragma unroll
    for (int n = 0; n < 4; ++n) accY[m][n] = (f32x4){0.f, 0.f, 0.f, 0.f};

  const float* gbase = Gt + (size_t)bc * CSc * CSc;
  const int kslim = 2 * wid + 2;      // triangle: skip K-steps above diagonal
  for (int ks = 0; ks < kslim; ++ks) {
    short8_t bv[4];
#pragma unroll
    for (int pb = 0; pb < 4; ++pb)
      bv[pb] = *(const short8_t*)(hrF + ((ks * 4 + pb) * 64 + lane) * 8);
    const int sb2 = ks * 32 + kq * 8;
    short8_t av[4];
#pragma unroll
    for (int m = 0; m < 4; ++m) {
      const int l = L0 + m * 16 + fr;
      const float alm = al[m];
      union { short8_t v; ushort_t u[8]; } pk;
#pragma unroll
      for (int j = 0; j < 8; ++j) {
        const int s = sb2 + j;
        float g = gbase[(size_t)s * CSc + l];
        float w = g * __expf(alm - acs[s]) * dts[s];
        w = (s <= l) ? w : 0.f;     // mask (discards inf/NaN garbage)
        pk.u[j] = f2b_rtn(w);
      }
      av[m] = pk.v;
    }
#pragma unroll
    for (int m = 0; m < 4; ++m)
#pragma unroll
      for (int pb = 0; pb < 4; ++pb)
        accY[m][pb] = __builtin_amdgcn_mfma_f32_16x16x32_bf16(av[m], bv[pb],
                                                              accY[m][pb], 0, 0, 0);
  }

  // epilogue Y: row l = L0+m*16+kq*4+j, col p = pb*16+fr; add D*h
  const float Dh = Dp[h];
#pragma unroll
  for (int m = 0; m < 4; ++m) {
#pragma unroll
    for (int pb = 0; pb < 4; ++pb) {
      const int p = pb * 16 + fr;
#pragma unroll
      for (int j = 0; j < 4; ++j) {
        const int l = L0 + m * 16 + kq * 4 + j;
        const int off = ((l >> 5) * 4 + pb) * 512 +
                        (fr + ((l >> 3) & 3) * 16) * 8 + (l & 7);
        Y[(size_t)(tg + l) * INTERc + h * Pp + p] =
            accY[m][pb][j] + Dh * b2f(hrF[off]);
      }
    }
  }

  // ================= GEMM-S: S[p][n] (wave wid owns cols [32*wid, 32*wid+32)) ===
  f32x4 accS[4][2];
#pragma unroll
  for (int m = 0; m < 4; ++m)
#pragma unroll
    for (int n = 0; n < 2; ++n) accS[m][n] = (f32x4){0.f, 0.f, 0.f, 0.f};

  const int N0 = wid * 32;
  const float* btb = Bt + (size_t)b * Nn * Ss + c * CSc;
  for (int ks = 0; ks < 8; ++ks) {
    short8_t am[4];
#pragma unroll
    for (int m = 0; m < 4; ++m)
      am[m] = *(const short8_t*)(hrF + ((ks * 4 + m) * 64 + lane) * 8);
    const int l0 = ks * 32 + kq * 8;
    short8_t bn[2];
#pragma unroll
    for (int nf = 0; nf < 2; ++nf) {
      const int n = N0 + nf * 16 + fr;
      const float* bp = btb + (size_t)n * Ss + l0;
      float4 v0 = *(const float4*)bp;
      float4 v1 = *(const float4*)(bp + 4);
      union { short8_t v; ushort_t u[8]; } pk;
      pk.u[0] = f2b_rtn(v0.x * wdec[l0 + 0]);
      pk.u[1] = f2b_rtn(v0.y * wdec[l0 + 1]);
      pk.u[2] = f2b_rtn(v0.z * wdec[l0 + 2]);
      pk.u[3] = f2b_rtn(v0.w * wdec[l0 + 3]);
      pk.u[4] = f2b_rtn(v1.x * wdec[l0 + 4]);
      pk.u[5] = f2b_rtn(v1.y * wdec[l0 + 5]);
      pk.u[6] = f2b_rtn(v1.z * wdec[l0 + 6]);
      pk.u[7] = f2b_rtn(v1.w * wdec[l0 + 7]);
      bn[nf] = pk.v;
    }
#pragma unroll
    for (int m = 0; m < 4; ++m)
#pragma unroll
      for (int nf = 0; nf < 2; ++nf)
        accS[m][nf] = __builtin_amdgcn_mfma_f32_16x16x32_bf16(am[m], bn[nf],
                                                              accS[m][nf], 0, 0, 0);
  }

  // epilogue S: row p = m*16+kq*4+j, col n = N0+nf*16+fr
  float* sp = S + ((size_t)bc * Hh + h) * Pp * Nn;
#pragma unroll
  for (int m = 0; m < 4; ++m)
#pragma unroll
    for (int nf = 0; nf < 2; ++nf) {
      const int n = N0 + nf * 16 + fr;
#pragma unroll
      for (int j = 0; j < 4; ++j)
        sp[(size_t)(m * 16 + kq * 4 + j) * Nn + n] = accS[m][nf][j];
    }
}

// ---------------- inter-chunk state recurrence (8 steps, elementwise) ----------------
__global__ __launch_bounds__(256)
void state_combine(const float* __restrict__ S, const float* __restrict__ acumb,
                   float* __restrict__ R) {
  const int idx = blockIdx.x * 256 + threadIdx.x;   // Bb*Hh*Pp*Nn = 524288
  const int n = idx & 127;
  const int p = (idx >> 7) & 63;
  const int h = (idx >> 13) & 31;
  const int b = idx >> 18;
  float r = 0.f;
  for (int c = 0; c < NCc; ++c) {
    const int bc = b * NCc + c;
    const size_t off = (((size_t)bc * Hh + h) * Pp + p) * Nn + n;
    R[off] = r;                                     // incoming state for chunk c
    const float atot = acumb[((size_t)bc * Hh + h) * CSc + CSc - 1];
    r = r * __expf(atot) + S[off];
  }
}

// ---------------- SSD off-diagonal: Y += exp(acum)*C·R ----------------
__global__ __launch_bounds__(256)
void ssd_off(const float* __restrict__ Ct, const float* __restrict__ acumb,
             const float* __restrict__ R, float* __restrict__ Y) {
  const int blk = blockIdx.x;          // 2048 = 2*8*32*4
  const int pb = blk & 3;
  const int h  = (blk >> 2) & 31;
  const int c  = (blk >> 7) & 7;
  const int b  = blk >> 10;
  const int p0 = pb * 16;
  const int bc = b * NCc + c;
  const int tg = b * Ss + c * CSc;
  const int tid = threadIdx.x;

  __shared__ float stateT[Nn][20];   // [n][pp], padded
  {
    const size_t rbase = (((size_t)bc * Hh + h) * Pp + p0) * Nn;
    for (int i = tid; i < Nn * 16; i += 256) {
      const int pp = i >> 7, n = i & 127;
      stateT[n][pp] = R[rbase + (size_t)pp * Nn + n];
    }
  }
  __syncthreads();
  const int l = tid;
  const float el = __expf(acumb[((size_t)bc * Hh + h) * CSc + l]);
  float acc[16];
#pragma unroll
  for (int q = 0; q < 16; ++q) acc[q] = 0.f;
  const float* cp = Ct + (size_t)b * Nn * Ss + c * CSc + l;
#pragma unroll 4
  for (int n = 0; n < Nn; ++n) {
    float cv = cp[(size_t)n * Ss];
    ACC16(cv, &stateT[n][0]);
  }
  float* yp = Y + (size_t)(tg + l) * INTERc + h * Pp + p0;
  float4 y0 = ((float4*)yp)[0], y1 = ((float4*)yp)[1];
  float4 y2 = ((float4*)yp)[2], y3 = ((float4*)yp)[3];
  ((float4*)yp)[0] = make_float4(y0.x + el*acc[0],  y0.y + el*acc[1],  y0.z + el*acc[2],  y0.w + el*acc[3]);
  ((float4*)yp)[1] = make_float4(y1.x + el*acc[4],  y1.y + el*acc[5],  y1.z + el*acc[6],  y1.w + el*acc[7]);
  ((float4*)yp)[2] = make_float4(y2.x + el*acc[8],  y2.y + el*acc[9],  y2.z + el*acc[10], y2.w + el*acc[11]);
  ((float4*)yp)[3] = make_float4(y3.x + el*acc[12], y3.y + el*acc[13], y3.z + el*acc[14], y3.w + el*acc[15]);
}

// ---------------- gate * silu + RMSNorm -> bf16 ----------------
__global__ __launch_bounds__(256)
void gate_norm(const float* __restrict__ Y, const float* __restrict__ proj,
               const float* __restrict__ nw, ushort_t* __restrict__ g) {
  const int t = blockIdx.x;
  const int tid = threadIdx.x;
  const int lane = tid & 63, wv = tid >> 6;
  __shared__ float ws4[4];
  const float* yp = Y + (size_t)t * INTERc;
  const float* gp = proj + (size_t)t * PROJc;
  float vals[8];
  float ss = 0.f;
#pragma unroll
  for (int i = 0; i < 8; ++i) {
    const int cix = tid + (i << 8);
    float yv = yp[cix];
    float gv = gp[cix];
    float vv = yv * (gv / (1.f + __expf(-gv)));
    vals[i] = vv;
    ss += vv * vv;
  }
#pragma unroll
  for (int off = 32; off > 0; off >>= 1) ss += __shfl_xor(ss, off);
  if (lane == 0) ws4[wv] = ss;
  __syncthreads();
  const float tot = ws4[0] + ws4[1] + ws4[2] + ws4[3];
  const float sc = rsqrtf(tot * (1.f / INTERc) + 1e-5f);
  ushort_t* go = g + (size_t)t * INTERc;
#pragma unroll
  for (int i = 0; i < 8; ++i) {
    const int cix = tid + (i << 8);
    go[cix] = f2b_rtn(vals[i] * sc * nw[cix]);
  }
}

extern "C" void kernel_launch(void* const* d_in, const int* in_sizes, int n_in,
                              void* d_out, int out_size, void* d_ws, size_t ws_size,
                              hipStream_t stream) {
  (void)in_sizes; (void)n_in; (void)out_size; (void)ws_size;
  const float* x       = (const float*)d_in[0];
  const float* W_in    = (const float*)d_in[1];
  const float* b_in    = (const float*)d_in[2];
  const float* conv_w  = (const float*)d_in[3];
  const float* dt_bias = (const float*)d_in[4];
  const float* A_log   = (const float*)d_in[5];
  const float* Dp      = (const float*)d_in[6];
  const float* norm_w  = (const float*)d_in[7];
  const float* W_out   = (const float*)d_in[8];
  const float* b_out   = (const float*)d_in[9];
  float* out = (float*)d_out;

  float* proj  = (float*)d_ws;
  float* conv  = proj  + (size_t)Tt * PROJc;
  float* dtv   = conv  + (size_t)Tt * CONVDc;
  float* adt   = dtv   + (size_t)Tt * Hh;
  float* Bt    = adt   + (size_t)Tt * Hh;
  float* Ct    = Bt    + (size_t)Bb * Nn * Ss;
  float* Gt    = Ct    + (size_t)Bb * Nn * Ss;
  float* acumb = Gt    + (size_t)Bb * NCc * CSc * CSc;
  float* dtc   = acumb + (size_t)Bb * NCc * Hh * CSc;
  float* Sbuf  = dtc   + (size_t)Bb * NCc * Hh * CSc;
  float* Roff  = Sbuf  + (size_t)Bb * NCc * Hh * Pp * Nn;
  float* Ybuf  = Roff  + (size_t)Bb * NCc * Hh * Pp * Nn;

  // bf16 overlays on regions dead at use time (stream-ordered):
  ushort_t* xb  = (ushort_t*)Sbuf;   // read @GEMM1; Sbuf written @ssd_intra
  ushort_t* Wib = (ushort_t*)Roff;   // read @GEMM1; Roff written @state_combine (4608 rows fit)
  ushort_t* Wob = (ushort_t*)Gt;     // converted after ssd_intra's last Gt read
  ushort_t* gbb = (ushort_t*)conv;   // written @gate_norm, after ssd_intra

  // 0. fp32->bf16 conversions for GEMM1
  f2b_kernel<<<(Tt * HIDc / 8 + 255) / 256, 256, 0, stream>>>(x, xb, Tt * HIDc / 8);
  f2b_kernel<<<(PROJc * HIDc / 8 + 255) / 256, 256, 0, stream>>>(
      W_in, Wib, PROJc * HIDc / 8);
  // 1. proj = x @ W_in^T + b_in  (256^2 2-phase MFMA)
  gemm256<<<(PROJ_PAD / 256) * (Tt / 256), 512, 0, stream>>>(
      xb, Wib, b_in, proj, Tt, PROJc, HIDc, PROJ_PAD / 256);
  // 2. conv + silu
  conv_silu<<<(Tt * CONVDc) / 256, 256, 0, stream>>>(proj, conv_w, conv);
  // 3. dt
  dt_kernel<<<(Tt * Hh) / 256, 256, 0, stream>>>(proj, dt_bias, A_log, dtv, adt);
  // 4. chunk-local scan of A*dt
  scan_kernel<<<Bb * NCc * Hh, 256, 0, stream>>>(adt, dtv, acumb, dtc);
  // 5. B/C transpose
  bc_transpose<<<(Bb * Nn * Ss) / 256, 256, 0, stream>>>(conv, Bt, Ct);
  // 6. G matrix (transposed storage, lower tri only)
  g_kernel<<<dim3(64, 4, 16), 256, 0, stream>>>(Bt, Ct, Gt);
  // 7. SSD intra-chunk via MFMA (Y_diag + D + chunk states)
  ssd_intra<<<Bb * NCc * Hh, 256, 0, stream>>>(conv, acumb, dtc, Gt, Bt, Dp,
                                               Ybuf, Sbuf);
  // 8. inter-chunk recurrence
  state_combine<<<(Bb * Hh * Pp * Nn) / 256, 256, 0, stream>>>(Sbuf, acumb, Roff);
  // 9. SSD off-diagonal
  ssd_off<<<Bb * NCc * Hh * 4, 256, 0, stream>>>(Ct, acumb, Roff, Ybuf);
  // 10. W_out -> bf16 (Gt dead after step 7)
  f2b_kernel<<<(HIDc * INTERc / 8 + 255) / 256, 256, 0, stream>>>(
      W_out, Wob, HIDc * INTERc / 8);
  // 11. gate + RMSNorm -> bf16 (conv dead after step 7)
  gate_norm<<<Tt, 256, 0, stream>>>(Ybuf, proj, norm_w, gbb);
  // 12. out = g @ W_out^T + b_out  (128^2 2-phase MFMA)
  gemm_bf16<<<(HIDc / 128) * (Tt / 128), 256, 0, stream>>>(
      gbb, Wob, b_out, out, Tt, HIDc, INTERc, HIDc / 128);
}